// Round 2
// baseline (703.164 us; speedup 1.0000x reference)
//
#include <hip/hip_runtime.h>
#include <hip/hip_bf16.h>

#define TT 336
#define NF 321
#define NB 64
#define NSER (NB * NF)   // 20544 series
#define WPB 4            // waves (series) per block in series_k

// ---------------------------------------------------------------------------
// Kernel 1: transpose [B, T, F] -> interleaved float2{tg,fc}[B*F][T], fused MSE
// ---------------------------------------------------------------------------
__global__ __launch_bounds__(256) void transpose_k(const float* __restrict__ fc,
                                                   const float* __restrict__ tg,
                                                   float2* __restrict__ out,
                                                   double* __restrict__ acc) {
    __shared__ float ta[32][33];
    __shared__ float tb[32][33];
    __shared__ double wacc[4];
    const int b = blockIdx.z;
    const int t0 = blockIdx.x * 32, f0 = blockIdx.y * 32;
    const int tx = threadIdx.x, ty = threadIdx.y;   // block (32, 8)
    const size_t base = (size_t)b * TT * NF;
    double ms = 0.0;
#pragma unroll
    for (int k = 0; k < 4; k++) {
        int t = t0 + ty + 8 * k, f = f0 + tx;
        if (t < TT && f < NF) {
            float a = tg[base + (size_t)t * NF + f];
            float c = fc[base + (size_t)t * NF + f];
            ta[ty + 8 * k][tx] = a;
            tb[ty + 8 * k][tx] = c;
            double d = (double)a - (double)c;
            ms += d * d;
        }
    }
    __syncthreads();
#pragma unroll
    for (int k = 0; k < 4; k++) {
        int f = f0 + ty + 8 * k, t = t0 + tx;
        if (t < TT && f < NF) {
            out[((size_t)b * NF + f) * TT + t] =
                make_float2(ta[tx][ty + 8 * k], tb[tx][ty + 8 * k]);
        }
    }
    for (int off = 32; off; off >>= 1) ms += __shfl_down(ms, off, 64);
    int flat = ty * 32 + tx;
    int lane = flat & 63, wid = flat >> 6;
    if (lane == 0) wacc[wid] = ms;
    __syncthreads();
    if (flat == 0) atomicAdd(&acc[0], wacc[0] + wacc[1] + wacc[2] + wacc[3]);
}

// ---------------------------------------------------------------------------
// MSE-only kernel (fallback path when workspace too small for transpose)
// ---------------------------------------------------------------------------
__global__ void mse_k(const float* __restrict__ fc, const float* __restrict__ tg,
                      double* __restrict__ acc) {
    const size_t N4 = (size_t)NB * TT * NF / 4;
    const float4* a4 = (const float4*)fc;
    const float4* b4 = (const float4*)tg;
    double s = 0.0;
    for (size_t i = (size_t)blockIdx.x * blockDim.x + threadIdx.x; i < N4;
         i += (size_t)gridDim.x * blockDim.x) {
        float4 a = a4[i], b = b4[i];
        double d0 = (double)a.x - (double)b.x;
        double d1 = (double)a.y - (double)b.y;
        double d2 = (double)a.z - (double)b.z;
        double d3 = (double)a.w - (double)b.w;
        s += d0 * d0 + d1 * d1 + d2 * d2 + d3 * d3;
    }
    for (int off = 32; off; off >>= 1) s += __shfl_down(s, off, 64);
    __shared__ double wsum[4];
    int flat = threadIdx.x;
    int lane = flat & 63, wid = flat >> 6;
    if (lane == 0) wsum[wid] = s;
    __syncthreads();
    if (flat == 0) atomicAdd(&acc[0], wsum[0] + wsum[1] + wsum[2] + wsum[3]);
}

// ---------------------------------------------------------------------------
__device__ __forceinline__ double patch_loss(double S1, double S2, double S3,
                                             double S4, double S5, double nn) {
    double mt = S1 / nn, mf = S2 / nn;
    double tvs = S3 - nn * mt * mt; tvs = tvs > 0.0 ? tvs : 0.0;
    double fvs = S4 - nn * mf * mf; fvs = fvs > 0.0 ? fvs : 0.0;
    double num = S5 - nn * mt * mf;
    double corr = num / (sqrt(tvs * fvs) + 1e-8);
    double closs = 1.0 - fabs(corr);
    double tvar = tvs / (nn - 1.0), fvar = fvs / (nn - 1.0);
    double vloss = fabs(tvar - fvar) / (tvar + 1e-8);
    double mloss = fabs(mt - mf) / (fabs(mt) + 1e-8);
    return closs + vloss + mloss;
}

// ---------------------------------------------------------------------------
// Kernel 2: per-series structural loss. 4 waves/block, one series per wave.
// acc[1] += sum of patch losses, acc[2] += patch count  (fp64 atomics)
// ---------------------------------------------------------------------------
__global__ __launch_bounds__(256, 6) void series_k(const float2* __restrict__ tsG,
                                                   const float* __restrict__ fcG,
                                                   const float* __restrict__ tgG,
                                                   int transposed,
                                                   double* __restrict__ acc) {
    const int w = threadIdx.x >> 6, lane = threadIdx.x & 63;
    const int ser = blockIdx.x * WPB + w;
    __shared__ float2 ts[WPB][TT];   // {tg, fc} interleaved
    __shared__ float4 zb[WPB][84];

    // ---- load series into LDS ----
    if (transposed) {
        const float2* sp = tsG + (size_t)ser * TT;
        for (int t = lane; t < TT; t += 64) ts[w][t] = sp[t];
    } else {
        int b = ser / NF, f = ser - b * NF;
        const float* tp = tgG + (size_t)b * TT * NF + f;
        const float* fp = fcG + (size_t)b * TT * NF + f;
        for (int t = lane; t < TT; t += 64)
            ts[w][t] = make_float2(tp[(size_t)t * NF], fp[(size_t)t * NF]);
    }
    __syncthreads();

    // ---- radix-4 fold: W_336^84 = -i.  z_f[t] depends only on f mod 4 ----
    for (int t = lane; t < 84; t += 64) {
        float x0 = ts[w][t].x, x1 = ts[w][t + 84].x;
        float x2 = ts[w][t + 168].x, x3 = ts[w][t + 252].x;
        float a = x0 + x2, b2 = x1 + x3, c = x0 - x2, d = x1 - x3;
        zb[w][t] = make_float4(a + b2, a - b2, c, d);
    }
    __syncthreads();

    // ---- DFT magnitudes, bins f = 1..168, 3 bins per lane (fused loop) ----
    const double TWOPI = 6.283185307179586476925286766559;
    int fb[3] = {1 + lane, 65 + lane, 129 + lane};
    float cc[3], sn[3], re[3], im[3], cd[3], sd[3], sgn[3];
    int selA[3];
#pragma unroll
    for (int q = 0; q < 3; q++) {
        int f = fb[q], cls = f & 3;
        double dl = (double)f * (TWOPI / 336.0);
        cd[q] = (float)cos(dl);
        sd[q] = (float)sin(dl);
        cc[q] = 1.0f; sn[q] = 0.0f; re[q] = 0.0f; im[q] = 0.0f;
        sgn[q] = (cls == 1) ? -1.0f : ((cls == 3) ? 1.0f : 0.0f);
        selA[q] = (cls == 0) ? 0 : ((cls == 2) ? 1 : 2);
    }
    for (int t = 0; t < 84; t++) {
        float4 zv = zb[w][t];
#pragma unroll
        for (int q = 0; q < 3; q++) {
            float zr = (selA[q] == 0) ? zv.x : ((selA[q] == 1) ? zv.y : zv.z);
            float zi = sgn[q] * zv.w;
            re[q] = fmaf(zr, cc[q], re[q]);
            re[q] = fmaf(zi, sn[q], re[q]);
            im[q] = fmaf(zi, cc[q], im[q]);
            im[q] = fmaf(-zr, sn[q], im[q]);
            float nc = fmaf(cc[q], cd[q], -(sn[q] * sd[q]));
            float ns = fmaf(sn[q], cd[q], cc[q] * sd[q]);
            cc[q] = nc; sn[q] = ns;
        }
    }

    // ---- top-3 by amplitude (ties -> lower freq), 64-bit keys ----
    unsigned long long k0 = 0, k1 = 0, k2 = 0;
    auto INS = [&](unsigned long long x) {
        unsigned long long hi = (k0 > x) ? k0 : x;
        unsigned long long lo = (k0 > x) ? x : k0;
        k0 = hi;
        unsigned long long hi1 = (k1 > lo) ? k1 : lo;
        unsigned long long lo1 = (k1 > lo) ? lo : k1;
        k1 = hi1;
        k2 = (k2 > lo1) ? k2 : lo1;
    };
#pragma unroll
    for (int q = 0; q < 3; q++) {
        float a2 = fmaf(re[q], re[q], im[q] * im[q]);
        unsigned long long key =
            ((unsigned long long)__float_as_uint(a2) << 32) |
            (unsigned long long)(0xFFFFFFFFu - (unsigned)fb[q]);
        if (fb[q] > 168) key = 0ull;
        INS(key);
    }
    for (int m = 1; m < 64; m <<= 1) {
        unsigned long long b0 = __shfl_xor(k0, m, 64);
        unsigned long long b1 = __shfl_xor(k1, m, 64);
        unsigned long long b2 = __shfl_xor(k2, m, 64);
        INS(b0); INS(b1); INS(b2);
    }

    // ---- periods, validity, segment counts (wave-uniform) ----
    int fr0 = (int)(0xFFFFFFFFu - (unsigned)(k0 & 0xFFFFFFFFull));
    int fr1 = (int)(0xFFFFFFFFu - (unsigned)(k1 & 0xFFFFFFFFull));
    int fr2 = (int)(0xFFFFFFFFu - (unsigned)(k2 & 0xFFFFFFFFull));
    int P[3] = {TT / fr0, TT / fr1, TT / fr2};
    bool vp[3];
    vp[0] = (P[0] >= 5);
    vp[1] = (P[1] >= 5) && (P[1] != P[0]);
    vp[2] = (P[2] >= 5) && (P[2] != P[0]) && (P[2] != P[1]);
    int nseg[3], rs[3];
    bool hr[3];
#pragma unroll
    for (int q = 0; q < 3; q++) {
        nseg[q] = TT / P[q];
        rs[q] = nseg[q] * P[q];
        hr[q] = vp[q] && ((TT - rs[q]) >= 5);
    }

    // ---- enumerate candidate patches (3 periods x 68 slots), dedup,
    //      direct fp64 per-patch sums from LDS ----
    double lsum = 0.0, lcnt = 0.0;
    unsigned long long anyMask = 0ull;
#pragma unroll
    for (int rI = 0; rI < 4; rI++) {
        int i = lane + 64 * rI;
        bool kept = false;
        int s = 0, e = 0;
        if (i < 204) {
            int k = (i >= 136) ? 2 : ((i >= 68) ? 1 : 0);
            int si = i - k * 68;
            if (vp[k]) {
                if (si < nseg[k]) { s = P[k] * si; e = s + P[k]; kept = true; }
                else if (si == nseg[k] && hr[k]) { s = rs[k]; e = TT; kept = true; }
                if (kept) {
#pragma unroll
                    for (int j = 0; j < 2; j++) {
                        if (j < k && vp[j]) {
                            bool dup = (s == rs[j]) && (e == TT) && hr[j];
                            int len = e - s;
                            if (len == P[j] && (s % P[j]) == 0 && (s / P[j]) < nseg[j]) dup = true;
                            if (dup) kept = false;
                        }
                    }
                }
            }
        }
        anyMask |= __ballot(kept);
        if (kept) {
            double S1 = 0, S2 = 0, S3 = 0, S4 = 0, S5 = 0;
            for (int t = s; t < e; t++) {
                float2 v = ts[w][t];
                double a = (double)v.x, b = (double)v.y;
                S1 += a; S2 += b;
                S3 += a * a; S4 += b * b; S5 += a * b;
            }
            lsum += patch_loss(S1, S2, S3, S4, S5, (double)(e - s));
            lcnt += 1.0;
        }
    }

    // ---- fallback whole-series patch (cooperative across the wave) ----
    if (anyMask == 0ull) {
        double S1 = 0, S2 = 0, S3 = 0, S4 = 0, S5 = 0;
        for (int t = lane; t < TT; t += 64) {
            float2 v = ts[w][t];
            double a = (double)v.x, b = (double)v.y;
            S1 += a; S2 += b;
            S3 += a * a; S4 += b * b; S5 += a * b;
        }
        for (int off = 32; off; off >>= 1) {
            S1 += __shfl_down(S1, off, 64);
            S2 += __shfl_down(S2, off, 64);
            S3 += __shfl_down(S3, off, 64);
            S4 += __shfl_down(S4, off, 64);
            S5 += __shfl_down(S5, off, 64);
        }
        if (lane == 0) {
            lsum += patch_loss(S1, S2, S3, S4, S5, (double)TT);
            lcnt += 1.0;
        }
    }

    for (int off = 32; off; off >>= 1) {
        lsum += __shfl_down(lsum, off, 64);
        lcnt += __shfl_down(lcnt, off, 64);
    }
    if (lane == 0) {
        atomicAdd(&acc[1], lsum);
        atomicAdd(&acc[2], lcnt);
    }
}

// ---------------------------------------------------------------------------
// Kernel 3: combine
// ---------------------------------------------------------------------------
__global__ void finalize_k(const double* __restrict__ acc, float* __restrict__ out) {
    double mse = acc[0] / (double)((size_t)NB * TT * NF);
    double avg = (acc[2] > 0.0) ? (acc[1] / acc[2]) : 0.0;
    out[0] = (float)(0.5 * mse + 0.5 * avg);
}

// ---------------------------------------------------------------------------
extern "C" void kernel_launch(void* const* d_in, const int* in_sizes, int n_in,
                              void* d_out, int out_size, void* d_ws, size_t ws_size,
                              hipStream_t stream) {
    const float* fc = (const float*)d_in[0];   // forecast
    const float* tg = (const float*)d_in[1];   // target
    float* out = (float*)d_out;
    char* ws = (char*)d_ws;
    double* acc = (double*)ws;                  // [0]=mse_sum [1]=loss_sum [2]=count

    const size_t offT = 64;
    const size_t bytesT = (size_t)NSER * TT * sizeof(float2);
    const bool do_transpose = (ws_size >= offT + bytesT);
    float2* tsT = (float2*)(ws + offT);

    hipMemsetAsync(d_ws, 0, 64, stream);

    if (do_transpose) {
        dim3 g((TT + 31) / 32, (NF + 31) / 32, NB);
        dim3 b(32, 8);
        transpose_k<<<g, b, 0, stream>>>(fc, tg, tsT, acc);
        series_k<<<NSER / WPB, 64 * WPB, 0, stream>>>(tsT, fc, tg, 1, acc);
    } else {
        mse_k<<<1024, 256, 0, stream>>>(fc, tg, acc);
        series_k<<<NSER / WPB, 64 * WPB, 0, stream>>>(nullptr, fc, tg, 0, acc);
    }
    finalize_k<<<1, 1, 0, stream>>>(acc, out);
}

// Round 3
// 257.909 us; speedup vs baseline: 2.7264x; 2.7264x over previous
//
#include <hip/hip_runtime.h>
#include <hip/hip_bf16.h>

#define TT 336
#define NF 321
#define NB 64
#define NSER (NB * NF)   // 20544 series
#define WPB 4            // waves (series) per block in series_k

// transpose grid: 11 x 11 x 64 blocks
#define TGX 11
#define TGY 11
#define NMSEP (TGX * TGY * NB)   // 7744 per-block MSE partials

// ---------------------------------------------------------------------------
// Kernel 1: transpose [B, T, F] -> interleaved float2{tg,fc}[B*F][T], fused MSE.
// Per-block MSE partial -> msep[block] (no atomics) unless msep==nullptr.
// ---------------------------------------------------------------------------
__global__ __launch_bounds__(256) void transpose_k(const float* __restrict__ fc,
                                                   const float* __restrict__ tg,
                                                   float2* __restrict__ out,
                                                   double* __restrict__ msep,
                                                   double* __restrict__ acc) {
    __shared__ float ta[32][33];
    __shared__ float tb[32][33];
    __shared__ double wacc[4];
    const int b = blockIdx.z;
    const int t0 = blockIdx.x * 32, f0 = blockIdx.y * 32;
    const int tx = threadIdx.x, ty = threadIdx.y;   // block (32, 8)
    const size_t base = (size_t)b * TT * NF;
    double ms = 0.0;
#pragma unroll
    for (int k = 0; k < 4; k++) {
        int t = t0 + ty + 8 * k, f = f0 + tx;
        if (t < TT && f < NF) {
            float a = tg[base + (size_t)t * NF + f];
            float c = fc[base + (size_t)t * NF + f];
            ta[ty + 8 * k][tx] = a;
            tb[ty + 8 * k][tx] = c;
            double d = (double)a - (double)c;
            ms += d * d;
        }
    }
    __syncthreads();
#pragma unroll
    for (int k = 0; k < 4; k++) {
        int f = f0 + ty + 8 * k, t = t0 + tx;
        if (t < TT && f < NF) {
            out[((size_t)b * NF + f) * TT + t] =
                make_float2(ta[tx][ty + 8 * k], tb[tx][ty + 8 * k]);
        }
    }
    for (int off = 32; off; off >>= 1) ms += __shfl_down(ms, off, 64);
    int flat = ty * 32 + tx;
    int lane = flat & 63, wid = flat >> 6;
    if (lane == 0) wacc[wid] = ms;
    __syncthreads();
    if (flat == 0) {
        double tot = wacc[0] + wacc[1] + wacc[2] + wacc[3];
        if (msep) {
            int blk = (blockIdx.z * TGY + blockIdx.y) * TGX + blockIdx.x;
            msep[blk] = tot;
        } else {
            atomicAdd(&acc[0], tot);
        }
    }
}

// ---------------------------------------------------------------------------
// MSE-only kernel (fallback path when workspace too small for transpose)
// ---------------------------------------------------------------------------
__global__ void mse_k(const float* __restrict__ fc, const float* __restrict__ tg,
                      double* __restrict__ acc) {
    const size_t N4 = (size_t)NB * TT * NF / 4;
    const float4* a4 = (const float4*)fc;
    const float4* b4 = (const float4*)tg;
    double s = 0.0;
    for (size_t i = (size_t)blockIdx.x * blockDim.x + threadIdx.x; i < N4;
         i += (size_t)gridDim.x * blockDim.x) {
        float4 a = a4[i], b = b4[i];
        double d0 = (double)a.x - (double)b.x;
        double d1 = (double)a.y - (double)b.y;
        double d2 = (double)a.z - (double)b.z;
        double d3 = (double)a.w - (double)b.w;
        s += d0 * d0 + d1 * d1 + d2 * d2 + d3 * d3;
    }
    for (int off = 32; off; off >>= 1) s += __shfl_down(s, off, 64);
    __shared__ double wsum[4];
    int flat = threadIdx.x;
    int lane = flat & 63, wid = flat >> 6;
    if (lane == 0) wsum[wid] = s;
    __syncthreads();
    if (flat == 0) atomicAdd(&acc[0], wsum[0] + wsum[1] + wsum[2] + wsum[3]);
}

// ---------------------------------------------------------------------------
__device__ __forceinline__ double patch_loss(double S1, double S2, double S3,
                                             double S4, double S5, double nn) {
    double mt = S1 / nn, mf = S2 / nn;
    double tvs = S3 - nn * mt * mt; tvs = tvs > 0.0 ? tvs : 0.0;
    double fvs = S4 - nn * mf * mf; fvs = fvs > 0.0 ? fvs : 0.0;
    double num = S5 - nn * mt * mf;
    double corr = num / (sqrt(tvs * fvs) + 1e-8);
    double closs = 1.0 - fabs(corr);
    double tvar = tvs / (nn - 1.0), fvar = fvs / (nn - 1.0);
    double vloss = fabs(tvar - fvar) / (tvar + 1e-8);
    double mloss = fabs(mt - mf) / (fabs(mt) + 1e-8);
    return closs + vloss + mloss;
}

// ---------------------------------------------------------------------------
// Kernel 2: per-series structural loss. 4 waves/block, one series per wave.
// Writes (lsum, lcnt) per series into pairs[ser] (no atomics) unless
// pairs==nullptr (fallback: fp64 atomics into acc[1]/acc[2]).
// ---------------------------------------------------------------------------
__global__ __launch_bounds__(256, 6) void series_k(const float2* __restrict__ tsG,
                                                   const float* __restrict__ fcG,
                                                   const float* __restrict__ tgG,
                                                   int transposed,
                                                   double2* __restrict__ pairs,
                                                   double* __restrict__ acc) {
    const int w = threadIdx.x >> 6, lane = threadIdx.x & 63;
    const int ser = blockIdx.x * WPB + w;
    __shared__ float2 ts[WPB][TT];   // {tg, fc} interleaved
    __shared__ float4 zb[WPB][84];

    // ---- load series into LDS ----
    if (transposed) {
        const float2* sp = tsG + (size_t)ser * TT;
        for (int t = lane; t < TT; t += 64) ts[w][t] = sp[t];
    } else {
        int b = ser / NF, f = ser - b * NF;
        const float* tp = tgG + (size_t)b * TT * NF + f;
        const float* fp = fcG + (size_t)b * TT * NF + f;
        for (int t = lane; t < TT; t += 64)
            ts[w][t] = make_float2(tp[(size_t)t * NF], fp[(size_t)t * NF]);
    }
    __syncthreads();

    // ---- radix-4 fold: W_336^84 = -i.  z_f[t] depends only on f mod 4 ----
    for (int t = lane; t < 84; t += 64) {
        float x0 = ts[w][t].x, x1 = ts[w][t + 84].x;
        float x2 = ts[w][t + 168].x, x3 = ts[w][t + 252].x;
        float a = x0 + x2, b2 = x1 + x3, c = x0 - x2, d = x1 - x3;
        zb[w][t] = make_float4(a + b2, a - b2, c, d);
    }
    __syncthreads();

    // ---- DFT magnitudes, bins f = 1..168, 3 bins per lane (fused loop) ----
    const double TWOPI = 6.283185307179586476925286766559;
    int fb[3] = {1 + lane, 65 + lane, 129 + lane};
    float cc[3], sn[3], re[3], im[3], cd[3], sd[3], sgn[3];
    int selA[3];
#pragma unroll
    for (int q = 0; q < 3; q++) {
        int f = fb[q], cls = f & 3;
        double dl = (double)f * (TWOPI / 336.0);
        cd[q] = (float)cos(dl);
        sd[q] = (float)sin(dl);
        cc[q] = 1.0f; sn[q] = 0.0f; re[q] = 0.0f; im[q] = 0.0f;
        sgn[q] = (cls == 1) ? -1.0f : ((cls == 3) ? 1.0f : 0.0f);
        selA[q] = (cls == 0) ? 0 : ((cls == 2) ? 1 : 2);
    }
    for (int t = 0; t < 84; t++) {
        float4 zv = zb[w][t];
#pragma unroll
        for (int q = 0; q < 3; q++) {
            float zr = (selA[q] == 0) ? zv.x : ((selA[q] == 1) ? zv.y : zv.z);
            float zi = sgn[q] * zv.w;
            re[q] = fmaf(zr, cc[q], re[q]);
            re[q] = fmaf(zi, sn[q], re[q]);
            im[q] = fmaf(zi, cc[q], im[q]);
            im[q] = fmaf(-zr, sn[q], im[q]);
            float nc = fmaf(cc[q], cd[q], -(sn[q] * sd[q]));
            float ns = fmaf(sn[q], cd[q], cc[q] * sd[q]);
            cc[q] = nc; sn[q] = ns;
        }
    }

    // ---- top-3 by amplitude (ties -> lower freq), 64-bit keys ----
    unsigned long long k0 = 0, k1 = 0, k2 = 0;
    auto INS = [&](unsigned long long x) {
        unsigned long long hi = (k0 > x) ? k0 : x;
        unsigned long long lo = (k0 > x) ? x : k0;
        k0 = hi;
        unsigned long long hi1 = (k1 > lo) ? k1 : lo;
        unsigned long long lo1 = (k1 > lo) ? lo : k1;
        k1 = hi1;
        k2 = (k2 > lo1) ? k2 : lo1;
    };
#pragma unroll
    for (int q = 0; q < 3; q++) {
        float a2 = fmaf(re[q], re[q], im[q] * im[q]);
        unsigned long long key =
            ((unsigned long long)__float_as_uint(a2) << 32) |
            (unsigned long long)(0xFFFFFFFFu - (unsigned)fb[q]);
        if (fb[q] > 168) key = 0ull;
        INS(key);
    }
    for (int m = 1; m < 64; m <<= 1) {
        unsigned long long b0 = __shfl_xor(k0, m, 64);
        unsigned long long b1 = __shfl_xor(k1, m, 64);
        unsigned long long b2 = __shfl_xor(k2, m, 64);
        INS(b0); INS(b1); INS(b2);
    }

    // ---- periods, validity, segment counts (wave-uniform) ----
    int fr0 = (int)(0xFFFFFFFFu - (unsigned)(k0 & 0xFFFFFFFFull));
    int fr1 = (int)(0xFFFFFFFFu - (unsigned)(k1 & 0xFFFFFFFFull));
    int fr2 = (int)(0xFFFFFFFFu - (unsigned)(k2 & 0xFFFFFFFFull));
    int P[3] = {TT / fr0, TT / fr1, TT / fr2};
    bool vp[3];
    vp[0] = (P[0] >= 5);
    vp[1] = (P[1] >= 5) && (P[1] != P[0]);
    vp[2] = (P[2] >= 5) && (P[2] != P[0]) && (P[2] != P[1]);
    int nseg[3], rs[3];
    bool hr[3];
#pragma unroll
    for (int q = 0; q < 3; q++) {
        nseg[q] = TT / P[q];
        rs[q] = nseg[q] * P[q];
        hr[q] = vp[q] && ((TT - rs[q]) >= 5);
    }

    // ---- enumerate candidate patches (3 periods x 68 slots), dedup,
    //      direct fp64 per-patch sums from LDS ----
    double lsum = 0.0, lcnt = 0.0;
    unsigned long long anyMask = 0ull;
#pragma unroll
    for (int rI = 0; rI < 4; rI++) {
        int i = lane + 64 * rI;
        bool kept = false;
        int s = 0, e = 0;
        if (i < 204) {
            int k = (i >= 136) ? 2 : ((i >= 68) ? 1 : 0);
            int si = i - k * 68;
            if (vp[k]) {
                if (si < nseg[k]) { s = P[k] * si; e = s + P[k]; kept = true; }
                else if (si == nseg[k] && hr[k]) { s = rs[k]; e = TT; kept = true; }
                if (kept) {
#pragma unroll
                    for (int j = 0; j < 2; j++) {
                        if (j < k && vp[j]) {
                            bool dup = (s == rs[j]) && (e == TT) && hr[j];
                            int len = e - s;
                            if (len == P[j] && (s % P[j]) == 0 && (s / P[j]) < nseg[j]) dup = true;
                            if (dup) kept = false;
                        }
                    }
                }
            }
        }
        anyMask |= __ballot(kept);
        if (kept) {
            double S1 = 0, S2 = 0, S3 = 0, S4 = 0, S5 = 0;
            for (int t = s; t < e; t++) {
                float2 v = ts[w][t];
                double a = (double)v.x, b = (double)v.y;
                S1 += a; S2 += b;
                S3 += a * a; S4 += b * b; S5 += a * b;
            }
            lsum += patch_loss(S1, S2, S3, S4, S5, (double)(e - s));
            lcnt += 1.0;
        }
    }

    // ---- fallback whole-series patch (cooperative across the wave) ----
    if (anyMask == 0ull) {
        double S1 = 0, S2 = 0, S3 = 0, S4 = 0, S5 = 0;
        for (int t = lane; t < TT; t += 64) {
            float2 v = ts[w][t];
            double a = (double)v.x, b = (double)v.y;
            S1 += a; S2 += b;
            S3 += a * a; S4 += b * b; S5 += a * b;
        }
        for (int off = 32; off; off >>= 1) {
            S1 += __shfl_down(S1, off, 64);
            S2 += __shfl_down(S2, off, 64);
            S3 += __shfl_down(S3, off, 64);
            S4 += __shfl_down(S4, off, 64);
            S5 += __shfl_down(S5, off, 64);
        }
        if (lane == 0) {
            lsum += patch_loss(S1, S2, S3, S4, S5, (double)TT);
            lcnt += 1.0;
        }
    }

    for (int off = 32; off; off >>= 1) {
        lsum += __shfl_down(lsum, off, 64);
        lcnt += __shfl_down(lcnt, off, 64);
    }
    if (lane == 0) {
        if (pairs) {
            pairs[ser] = make_double2(lsum, lcnt);
        } else {
            atomicAdd(&acc[1], lsum);
            atomicAdd(&acc[2], lcnt);
        }
    }
}

// ---------------------------------------------------------------------------
// Kernel 3: single-block final reduction over per-wave pairs + MSE partials
// ---------------------------------------------------------------------------
__global__ __launch_bounds__(1024) void reduce_k(const double2* __restrict__ pairs,
                                                 const double* __restrict__ msep,
                                                 float* __restrict__ out) {
    const int tid = threadIdx.x;
    double ls = 0.0, lc = 0.0, ms = 0.0;
    for (int i = tid; i < NSER; i += 1024) {
        double2 p = pairs[i];
        ls += p.x; lc += p.y;
    }
    for (int i = tid; i < NMSEP; i += 1024) ms += msep[i];
    for (int off = 32; off; off >>= 1) {
        ls += __shfl_down(ls, off, 64);
        lc += __shfl_down(lc, off, 64);
        ms += __shfl_down(ms, off, 64);
    }
    __shared__ double sl[16], sc[16], sm[16];
    int lane = tid & 63, wid = tid >> 6;
    if (lane == 0) { sl[wid] = ls; sc[wid] = lc; sm[wid] = ms; }
    __syncthreads();
    if (tid == 0) {
        double L = 0, C = 0, M = 0;
        for (int i = 0; i < 16; i++) { L += sl[i]; C += sc[i]; M += sm[i]; }
        double mse = M / (double)((size_t)NB * TT * NF);
        double avg = (C > 0.0) ? (L / C) : 0.0;
        out[0] = (float)(0.5 * mse + 0.5 * avg);
    }
}

// ---------------------------------------------------------------------------
// Fallback combine (atomic path)
// ---------------------------------------------------------------------------
__global__ void finalize_k(const double* __restrict__ acc, float* __restrict__ out) {
    double mse = acc[0] / (double)((size_t)NB * TT * NF);
    double avg = (acc[2] > 0.0) ? (acc[1] / acc[2]) : 0.0;
    out[0] = (float)(0.5 * mse + 0.5 * avg);
}

// ---------------------------------------------------------------------------
extern "C" void kernel_launch(void* const* d_in, const int* in_sizes, int n_in,
                              void* d_out, int out_size, void* d_ws, size_t ws_size,
                              hipStream_t stream) {
    const float* fc = (const float*)d_in[0];   // forecast
    const float* tg = (const float*)d_in[1];   // target
    float* out = (float*)d_out;
    char* ws = (char*)d_ws;
    double* acc = (double*)ws;                  // fallback accumulators

    // workspace layout (tight): [0,64) acc | msep | pairs | transposed series
    const size_t OFF_MSE = 64;
    const size_t OFF_PAIR = OFF_MSE + (size_t)NMSEP * sizeof(double);      // 62016
    const size_t OFF_TS = OFF_PAIR + (size_t)NSER * sizeof(double2);      // 390720
    const size_t bytesT = (size_t)NSER * TT * sizeof(float2);
    const bool big = (ws_size >= OFF_TS + bytesT);                 // new path
    const bool mid = !big && (ws_size >= OFF_MSE + bytesT);        // round-2 path

    double* msep = (double*)(ws + OFF_MSE);
    double2* pairs = (double2*)(ws + OFF_PAIR);
    float2* tsT = big ? (float2*)(ws + OFF_TS) : (float2*)(ws + OFF_MSE);

    hipMemsetAsync(d_ws, 0, 64, stream);

    dim3 tg_grid(TGX, TGY, NB);
    dim3 tg_blk(32, 8);
    if (big) {
        transpose_k<<<tg_grid, tg_blk, 0, stream>>>(fc, tg, tsT, msep, acc);
        series_k<<<NSER / WPB, 64 * WPB, 0, stream>>>(tsT, fc, tg, 1, pairs, acc);
        reduce_k<<<1, 1024, 0, stream>>>(pairs, msep, out);
    } else if (mid) {
        transpose_k<<<tg_grid, tg_blk, 0, stream>>>(fc, tg, tsT, nullptr, acc);
        series_k<<<NSER / WPB, 64 * WPB, 0, stream>>>(tsT, fc, tg, 1, nullptr, acc);
        finalize_k<<<1, 1, 0, stream>>>(acc, out);
    } else {
        mse_k<<<1024, 256, 0, stream>>>(fc, tg, acc);
        series_k<<<NSER / WPB, 64 * WPB, 0, stream>>>(nullptr, fc, tg, 0, nullptr, acc);
        finalize_k<<<1, 1, 0, stream>>>(acc, out);
    }
}

// Round 4
// 227.529 us; speedup vs baseline: 3.0904x; 1.1335x over previous
//
#include <hip/hip_runtime.h>
#include <hip/hip_bf16.h>

#define TT 336
#define NF 321
#define NB 64
#define NSER (NB * NF)   // 20544 series
#define WPB 4            // waves (series) per block in patch kernels
#define KP 352           // K padded to multiple of 32 for 16x16x32 MFMA
#define LDA 360          // LDS row stride (ushorts) in psd_k

// transpose grid: 11 x 11 x 64 blocks
#define TGX 11
#define TGY 11
#define NMSEP (TGX * TGY * NB)   // 7744 per-block MSE partials

typedef __attribute__((ext_vector_type(8))) short bf16x8;
typedef __attribute__((ext_vector_type(4))) float f32x4;
typedef unsigned long long ULL;

__device__ __forceinline__ unsigned short f2bf(float v) {
    unsigned x = __float_as_uint(v);
    x += 0x7FFFu + ((x >> 16) & 1u);   // RNE; inputs are finite
    return (unsigned short)(x >> 16);
}

// sorted-3 insert (a0 >= a1 >= a2)
__device__ __forceinline__ void ins3(ULL& a0, ULL& a1, ULL& a2, ULL x) {
    ULL hi = a0 > x ? a0 : x;
    ULL lo = a0 > x ? x : a0;
    a0 = hi;
    ULL hi1 = a1 > lo ? a1 : lo;
    ULL lo1 = a1 > lo ? lo : a1;
    a1 = hi1;
    a2 = a2 > lo1 ? a2 : lo1;
}

// ---------------------------------------------------------------------------
// Twiddle matrix: Wb[n][k], n=2(f-1) -> cos(2pi f k/336), n=2(f-1)+1 -> sin
// (sign of sin irrelevant: only |X|^2 is used). k in [336,352) zero-padded.
// ---------------------------------------------------------------------------
__global__ void twiddle_k(unsigned short* __restrict__ Wb) {
    int n = blockIdx.x;          // 0..335
    int f = (n >> 1) + 1;
    int isSin = n & 1;
    for (int k = threadIdx.x; k < KP; k += blockDim.x) {
        float v = 0.0f;
        if (k < TT) {
            int r = (f * k) % TT;
            double ang = 6.283185307179586476925286766559 * (double)r / 336.0;
            v = isSin ? (float)sin(ang) : (float)cos(ang);
        }
        Wb[(size_t)n * KP + k] = f2bf(v);
    }
}

// ---------------------------------------------------------------------------
// PSD + top-3 via MFMA GEMM. Block = 64 series, 4 waves; wave = 16-series
// stripe x all 336 cols. A: bf16 series tile (LDS). B: twiddle matrix (L2).
// C layout (m89-verified): col=lane&15, row=(lane>>4)*4+reg.
// A layout: A[m=lane&15][k=quad*8+j]; B: B[k=quad*8+j][n=lane&15].
// ---------------------------------------------------------------------------
__global__ __launch_bounds__(256) void psd_k(const float* __restrict__ tgO,
                                             const unsigned short* __restrict__ Wb,
                                             uint4* __restrict__ topk) {
    __shared__ __align__(16) unsigned short sA[64][LDA];
    const int tid = threadIdx.x;
    const int serBase = blockIdx.x * 64;

    // ---- stage A-tile (coalesced on feature dim of original layout) ----
    {
        int f_l = tid & 63, tch = tid >> 6;
        int ser = serBase + f_l;
        int bb = ser / NF, ff = ser - bb * NF;
        const float* base = tgO + (size_t)bb * TT * NF + ff;
        int t0 = tch * 84;
        for (int i = 0; i < 84; i++)
            sA[f_l][t0 + i] = f2bf(base[(size_t)(t0 + i) * NF]);
    }
    for (int idx = tid; idx < 64 * 16; idx += 256)
        sA[idx >> 4][TT + (idx & 15)] = 0;
    __syncthreads();

    const int wave = tid >> 6, lane = tid & 63;
    const int quad = lane >> 4, c = lane & 15;
    const unsigned short* aRow = &sA[wave * 16 + c][quad * 8];
    const unsigned short* bBase = Wb + (size_t)c * KP + quad * 8;

    f32x4 acc[21];
#pragma unroll
    for (int nt = 0; nt < 21; nt++) acc[nt] = (f32x4){0.f, 0.f, 0.f, 0.f};
    for (int ks = 0; ks < 11; ks++) {
        bf16x8 a = *(const bf16x8*)(aRow + ks * 32);
#pragma unroll
        for (int nt = 0; nt < 21; nt++) {
            bf16x8 b = *(const bf16x8*)(bBase + (size_t)nt * 16 * KP + ks * 32);
            acc[nt] = __builtin_amdgcn_mfma_f32_16x16x32_bf16(a, b, acc[nt], 0, 0, 0);
        }
    }

    // ---- PSD (pair adjacent cos/sin cols) + per-reg running top-3 ----
    ULL t0k[4] = {0, 0, 0, 0}, t1k[4] = {0, 0, 0, 0}, t2k[4] = {0, 0, 0, 0};
#pragma unroll
    for (int nt = 0; nt < 21; nt++) {
        unsigned fidx = (unsigned)(((nt * 16 + c) >> 1) + 1);
        unsigned ftag = 0xFFFFFFFFu - fidx;
        bool odd = (c & 1) != 0;
#pragma unroll
        for (int r = 0; r < 4; r++) {
            float v = acc[nt][r];
            float p = v * v;
            p += __shfl_xor(p, 1, 64);
            ULL key = odd ? 0ull
                          : (((ULL)__float_as_uint(p) << 32) | (ULL)ftag);
            ins3(t0k[r], t1k[r], t2k[r], key);
        }
    }
    // merge across the 8 even-c lanes of each quad (masks stay within quad)
#pragma unroll
    for (int m = 2; m <= 8; m <<= 1) {
#pragma unroll
        for (int r = 0; r < 4; r++) {
            ULL b0 = __shfl_xor(t0k[r], m, 64);
            ULL b1 = __shfl_xor(t1k[r], m, 64);
            ULL b2 = __shfl_xor(t2k[r], m, 64);
            ins3(t0k[r], t1k[r], t2k[r], b0);
            ins3(t0k[r], t1k[r], t2k[r], b1);
            ins3(t0k[r], t1k[r], t2k[r], b2);
        }
    }
    if (c == 0) {
#pragma unroll
        for (int r = 0; r < 4; r++) {
            unsigned f0 = 0xFFFFFFFFu - (unsigned)(t0k[r] & 0xFFFFFFFFull);
            unsigned f1 = 0xFFFFFFFFu - (unsigned)(t1k[r] & 0xFFFFFFFFull);
            unsigned f2 = 0xFFFFFFFFu - (unsigned)(t2k[r] & 0xFFFFFFFFull);
            topk[serBase + wave * 16 + quad * 4 + r] = make_uint4(f0, f1, f2, 0u);
        }
    }
}

// ---------------------------------------------------------------------------
// Kernel 1: transpose [B, T, F] -> interleaved float2{tg,fc}[B*F][T], fused MSE.
// ---------------------------------------------------------------------------
__global__ __launch_bounds__(256) void transpose_k(const float* __restrict__ fc,
                                                   const float* __restrict__ tg,
                                                   float2* __restrict__ out,
                                                   double* __restrict__ msep,
                                                   double* __restrict__ acc) {
    __shared__ float ta[32][33];
    __shared__ float tb[32][33];
    __shared__ double wacc[4];
    const int b = blockIdx.z;
    const int t0 = blockIdx.x * 32, f0 = blockIdx.y * 32;
    const int tx = threadIdx.x, ty = threadIdx.y;   // block (32, 8)
    const size_t base = (size_t)b * TT * NF;
    double ms = 0.0;
#pragma unroll
    for (int k = 0; k < 4; k++) {
        int t = t0 + ty + 8 * k, f = f0 + tx;
        if (t < TT && f < NF) {
            float a = tg[base + (size_t)t * NF + f];
            float c = fc[base + (size_t)t * NF + f];
            ta[ty + 8 * k][tx] = a;
            tb[ty + 8 * k][tx] = c;
            double d = (double)a - (double)c;
            ms += d * d;
        }
    }
    __syncthreads();
#pragma unroll
    for (int k = 0; k < 4; k++) {
        int f = f0 + ty + 8 * k, t = t0 + tx;
        if (t < TT && f < NF) {
            out[((size_t)b * NF + f) * TT + t] =
                make_float2(ta[tx][ty + 8 * k], tb[tx][ty + 8 * k]);
        }
    }
    for (int off = 32; off; off >>= 1) ms += __shfl_down(ms, off, 64);
    int flat = ty * 32 + tx;
    int lane = flat & 63, wid = flat >> 6;
    if (lane == 0) wacc[wid] = ms;
    __syncthreads();
    if (flat == 0) {
        double tot = wacc[0] + wacc[1] + wacc[2] + wacc[3];
        if (msep) {
            int blk = (blockIdx.z * TGY + blockIdx.y) * TGX + blockIdx.x;
            msep[blk] = tot;
        } else {
            atomicAdd(&acc[0], tot);
        }
    }
}

// ---------------------------------------------------------------------------
__global__ void mse_k(const float* __restrict__ fc, const float* __restrict__ tg,
                      double* __restrict__ acc) {
    const size_t N4 = (size_t)NB * TT * NF / 4;
    const float4* a4 = (const float4*)fc;
    const float4* b4 = (const float4*)tg;
    double s = 0.0;
    for (size_t i = (size_t)blockIdx.x * blockDim.x + threadIdx.x; i < N4;
         i += (size_t)gridDim.x * blockDim.x) {
        float4 a = a4[i], b = b4[i];
        double d0 = (double)a.x - (double)b.x;
        double d1 = (double)a.y - (double)b.y;
        double d2 = (double)a.z - (double)b.z;
        double d3 = (double)a.w - (double)b.w;
        s += d0 * d0 + d1 * d1 + d2 * d2 + d3 * d3;
    }
    for (int off = 32; off; off >>= 1) s += __shfl_down(s, off, 64);
    __shared__ double wsum[4];
    int flat = threadIdx.x;
    int lane = flat & 63, wid = flat >> 6;
    if (lane == 0) wsum[wid] = s;
    __syncthreads();
    if (flat == 0) atomicAdd(&acc[0], wsum[0] + wsum[1] + wsum[2] + wsum[3]);
}

// ---------------------------------------------------------------------------
__device__ __forceinline__ double patch_loss(double S1, double S2, double S3,
                                             double S4, double S5, double nn) {
    double mt = S1 / nn, mf = S2 / nn;
    double tvs = S3 - nn * mt * mt; tvs = tvs > 0.0 ? tvs : 0.0;
    double fvs = S4 - nn * mf * mf; fvs = fvs > 0.0 ? fvs : 0.0;
    double num = S5 - nn * mt * mf;
    double corr = num / (sqrt(tvs * fvs) + 1e-8);
    double closs = 1.0 - fabs(corr);
    double tvar = tvs / (nn - 1.0), fvar = fvs / (nn - 1.0);
    double vloss = fabs(tvar - fvar) / (tvar + 1e-8);
    double mloss = fabs(mt - mf) / (fabs(mt) + 1e-8);
    return closs + vloss + mloss;
}

// ---------------------------------------------------------------------------
// Shared patch-enumeration + stats body (freqs fr0>=amp fr1 fr2 given).
// ---------------------------------------------------------------------------
__device__ __forceinline__ void patch_body(const float2* tsw, int lane,
                                           int fr0, int fr1, int fr2,
                                           double& lsum, double& lcnt) {
    int P[3] = {TT / fr0, TT / fr1, TT / fr2};
    bool vp[3];
    vp[0] = (P[0] >= 5);
    vp[1] = (P[1] >= 5) && (P[1] != P[0]);
    vp[2] = (P[2] >= 5) && (P[2] != P[0]) && (P[2] != P[1]);
    int nseg[3], rs[3];
    bool hr[3];
#pragma unroll
    for (int q = 0; q < 3; q++) {
        nseg[q] = TT / P[q];
        rs[q] = nseg[q] * P[q];
        hr[q] = vp[q] && ((TT - rs[q]) >= 5);
    }
    unsigned long long anyMask = 0ull;
#pragma unroll
    for (int rI = 0; rI < 4; rI++) {
        int i = lane + 64 * rI;
        bool kept = false;
        int s = 0, e = 0;
        if (i < 204) {
            int k = (i >= 136) ? 2 : ((i >= 68) ? 1 : 0);
            int si = i - k * 68;
            if (vp[k]) {
                if (si < nseg[k]) { s = P[k] * si; e = s + P[k]; kept = true; }
                else if (si == nseg[k] && hr[k]) { s = rs[k]; e = TT; kept = true; }
                if (kept) {
#pragma unroll
                    for (int j = 0; j < 2; j++) {
                        if (j < k && vp[j]) {
                            bool dup = (s == rs[j]) && (e == TT) && hr[j];
                            int len = e - s;
                            if (len == P[j] && (s % P[j]) == 0 && (s / P[j]) < nseg[j]) dup = true;
                            if (dup) kept = false;
                        }
                    }
                }
            }
        }
        anyMask |= __ballot(kept);
        if (kept) {
            double S1 = 0, S2 = 0, S3 = 0, S4 = 0, S5 = 0;
            for (int t = s; t < e; t++) {
                float2 v = tsw[t];
                double a = (double)v.x, b = (double)v.y;
                S1 += a; S2 += b;
                S3 += a * a; S4 += b * b; S5 += a * b;
            }
            lsum += patch_loss(S1, S2, S3, S4, S5, (double)(e - s));
            lcnt += 1.0;
        }
    }
    if (anyMask == 0ull) {
        double S1 = 0, S2 = 0, S3 = 0, S4 = 0, S5 = 0;
        for (int t = lane; t < TT; t += 64) {
            float2 v = tsw[t];
            double a = (double)v.x, b = (double)v.y;
            S1 += a; S2 += b;
            S3 += a * a; S4 += b * b; S5 += a * b;
        }
        for (int off = 32; off; off >>= 1) {
            S1 += __shfl_down(S1, off, 64);
            S2 += __shfl_down(S2, off, 64);
            S3 += __shfl_down(S3, off, 64);
            S4 += __shfl_down(S4, off, 64);
            S5 += __shfl_down(S5, off, 64);
        }
        if (lane == 0) {
            lsum += patch_loss(S1, S2, S3, S4, S5, (double)TT);
            lcnt += 1.0;
        }
    }
}

// ---------------------------------------------------------------------------
// Kernel: patch stats only (freqs from psd_k). 4 waves/block, 1 series/wave.
// ---------------------------------------------------------------------------
__global__ __launch_bounds__(256) void patch_k(const float2* __restrict__ tsG,
                                               const uint4* __restrict__ topk,
                                               double2* __restrict__ pairs) {
    const int w = threadIdx.x >> 6, lane = threadIdx.x & 63;
    const int ser = blockIdx.x * WPB + w;
    __shared__ float2 ts[WPB][TT];
    const float2* sp = tsG + (size_t)ser * TT;
    for (int t = lane; t < TT; t += 64) ts[w][t] = sp[t];
    __syncthreads();

    uint4 tk = topk[ser];
    double lsum = 0.0, lcnt = 0.0;
    patch_body(&ts[w][0], lane, (int)tk.x, (int)tk.y, (int)tk.z, lsum, lcnt);

    for (int off = 32; off; off >>= 1) {
        lsum += __shfl_down(lsum, off, 64);
        lcnt += __shfl_down(lcnt, off, 64);
    }
    if (lane == 0) pairs[ser] = make_double2(lsum, lcnt);
}

// ---------------------------------------------------------------------------
// FALLBACK: old self-contained series kernel (VALU DFT + topk + patches).
// ---------------------------------------------------------------------------
__global__ __launch_bounds__(256, 6) void series_k(const float2* __restrict__ tsG,
                                                   const float* __restrict__ fcG,
                                                   const float* __restrict__ tgG,
                                                   int transposed,
                                                   double2* __restrict__ pairs,
                                                   double* __restrict__ acc) {
    const int w = threadIdx.x >> 6, lane = threadIdx.x & 63;
    const int ser = blockIdx.x * WPB + w;
    __shared__ float2 ts[WPB][TT];
    __shared__ float4 zb[WPB][84];

    if (transposed) {
        const float2* sp = tsG + (size_t)ser * TT;
        for (int t = lane; t < TT; t += 64) ts[w][t] = sp[t];
    } else {
        int b = ser / NF, f = ser - b * NF;
        const float* tp = tgG + (size_t)b * TT * NF + f;
        const float* fp = fcG + (size_t)b * TT * NF + f;
        for (int t = lane; t < TT; t += 64)
            ts[w][t] = make_float2(tp[(size_t)t * NF], fp[(size_t)t * NF]);
    }
    __syncthreads();

    for (int t = lane; t < 84; t += 64) {
        float x0 = ts[w][t].x, x1 = ts[w][t + 84].x;
        float x2 = ts[w][t + 168].x, x3 = ts[w][t + 252].x;
        float a = x0 + x2, b2 = x1 + x3, c = x0 - x2, d = x1 - x3;
        zb[w][t] = make_float4(a + b2, a - b2, c, d);
    }
    __syncthreads();

    const double TWOPI = 6.283185307179586476925286766559;
    int fb[3] = {1 + lane, 65 + lane, 129 + lane};
    float cc[3], sn[3], re[3], im[3], cd[3], sd[3], sgn[3];
    int selA[3];
#pragma unroll
    for (int q = 0; q < 3; q++) {
        int f = fb[q], cls = f & 3;
        double dl = (double)f * (TWOPI / 336.0);
        cd[q] = (float)cos(dl);
        sd[q] = (float)sin(dl);
        cc[q] = 1.0f; sn[q] = 0.0f; re[q] = 0.0f; im[q] = 0.0f;
        sgn[q] = (cls == 1) ? -1.0f : ((cls == 3) ? 1.0f : 0.0f);
        selA[q] = (cls == 0) ? 0 : ((cls == 2) ? 1 : 2);
    }
    for (int t = 0; t < 84; t++) {
        float4 zv = zb[w][t];
#pragma unroll
        for (int q = 0; q < 3; q++) {
            float zr = (selA[q] == 0) ? zv.x : ((selA[q] == 1) ? zv.y : zv.z);
            float zi = sgn[q] * zv.w;
            re[q] = fmaf(zr, cc[q], re[q]);
            re[q] = fmaf(zi, sn[q], re[q]);
            im[q] = fmaf(zi, cc[q], im[q]);
            im[q] = fmaf(-zr, sn[q], im[q]);
            float nc = fmaf(cc[q], cd[q], -(sn[q] * sd[q]));
            float ns = fmaf(sn[q], cd[q], cc[q] * sd[q]);
            cc[q] = nc; sn[q] = ns;
        }
    }

    ULL k0 = 0, k1 = 0, k2 = 0;
#pragma unroll
    for (int q = 0; q < 3; q++) {
        float a2 = fmaf(re[q], re[q], im[q] * im[q]);
        ULL key = ((ULL)__float_as_uint(a2) << 32) |
                  (ULL)(0xFFFFFFFFu - (unsigned)fb[q]);
        if (fb[q] > 168) key = 0ull;
        ins3(k0, k1, k2, key);
    }
    for (int m = 1; m < 64; m <<= 1) {
        ULL b0 = __shfl_xor(k0, m, 64);
        ULL b1 = __shfl_xor(k1, m, 64);
        ULL b2 = __shfl_xor(k2, m, 64);
        ins3(k0, k1, k2, b0); ins3(k0, k1, k2, b1); ins3(k0, k1, k2, b2);
    }

    int fr0 = (int)(0xFFFFFFFFu - (unsigned)(k0 & 0xFFFFFFFFull));
    int fr1 = (int)(0xFFFFFFFFu - (unsigned)(k1 & 0xFFFFFFFFull));
    int fr2 = (int)(0xFFFFFFFFu - (unsigned)(k2 & 0xFFFFFFFFull));

    double lsum = 0.0, lcnt = 0.0;
    patch_body(&ts[w][0], lane, fr0, fr1, fr2, lsum, lcnt);

    for (int off = 32; off; off >>= 1) {
        lsum += __shfl_down(lsum, off, 64);
        lcnt += __shfl_down(lcnt, off, 64);
    }
    if (lane == 0) {
        if (pairs) {
            pairs[ser] = make_double2(lsum, lcnt);
        } else {
            atomicAdd(&acc[1], lsum);
            atomicAdd(&acc[2], lcnt);
        }
    }
}

// ---------------------------------------------------------------------------
__global__ __launch_bounds__(1024) void reduce_k(const double2* __restrict__ pairs,
                                                 const double* __restrict__ msep,
                                                 float* __restrict__ out) {
    const int tid = threadIdx.x;
    double ls = 0.0, lc = 0.0, ms = 0.0;
    for (int i = tid; i < NSER; i += 1024) {
        double2 p = pairs[i];
        ls += p.x; lc += p.y;
    }
    for (int i = tid; i < NMSEP; i += 1024) ms += msep[i];
    for (int off = 32; off; off >>= 1) {
        ls += __shfl_down(ls, off, 64);
        lc += __shfl_down(lc, off, 64);
        ms += __shfl_down(ms, off, 64);
    }
    __shared__ double sl[16], sc[16], sm[16];
    int lane = tid & 63, wid = tid >> 6;
    if (lane == 0) { sl[wid] = ls; sc[wid] = lc; sm[wid] = ms; }
    __syncthreads();
    if (tid == 0) {
        double L = 0, C = 0, M = 0;
        for (int i = 0; i < 16; i++) { L += sl[i]; C += sc[i]; M += sm[i]; }
        double mse = M / (double)((size_t)NB * TT * NF);
        double avg = (C > 0.0) ? (L / C) : 0.0;
        out[0] = (float)(0.5 * mse + 0.5 * avg);
    }
}

__global__ void finalize_k(const double* __restrict__ acc, float* __restrict__ out) {
    double mse = acc[0] / (double)((size_t)NB * TT * NF);
    double avg = (acc[2] > 0.0) ? (acc[1] / acc[2]) : 0.0;
    out[0] = (float)(0.5 * mse + 0.5 * avg);
}

// ---------------------------------------------------------------------------
extern "C" void kernel_launch(void* const* d_in, const int* in_sizes, int n_in,
                              void* d_out, int out_size, void* d_ws, size_t ws_size,
                              hipStream_t stream) {
    const float* fc = (const float*)d_in[0];   // forecast
    const float* tg = (const float*)d_in[1];   // target
    float* out = (float*)d_out;
    char* ws = (char*)d_ws;
    double* acc = (double*)ws;

    // layout: [0,64) acc | msep | pairs | topk | Wb | tsT
    const size_t OFF_MSE = 64;
    const size_t OFF_PAIR = OFF_MSE + (size_t)NMSEP * sizeof(double);        // 62016
    const size_t OFF_TOP = OFF_PAIR + (size_t)NSER * sizeof(double2);        // 390720
    const size_t OFF_W = OFF_TOP + (size_t)NSER * sizeof(uint4);             // 719424
    const size_t OFF_TS = OFF_W + (size_t)TT * KP * sizeof(unsigned short);  // 955968
    const size_t bytesT = (size_t)NSER * TT * sizeof(float2);
    const bool big2 = (ws_size >= OFF_TS + bytesT);
    // round-3 fallback layout
    const size_t R3_OFF_TS = OFF_PAIR + (size_t)NSER * sizeof(double2);
    const bool big = !big2 && (ws_size >= R3_OFF_TS + bytesT);
    const bool mid = !big2 && !big && (ws_size >= OFF_MSE + bytesT);

    double* msep = (double*)(ws + OFF_MSE);
    double2* pairs = (double2*)(ws + OFF_PAIR);
    uint4* topkBuf = (uint4*)(ws + OFF_TOP);
    unsigned short* Wb = (unsigned short*)(ws + OFF_W);

    dim3 tg_grid(TGX, TGY, NB);
    dim3 tg_blk(32, 8);

    if (big2) {
        float2* tsT = (float2*)(ws + OFF_TS);
        twiddle_k<<<TT, 128, 0, stream>>>(Wb);
        transpose_k<<<tg_grid, tg_blk, 0, stream>>>(fc, tg, tsT, msep, acc);
        psd_k<<<NSER / 64, 256, 0, stream>>>(tg, Wb, topkBuf);
        patch_k<<<NSER / WPB, 64 * WPB, 0, stream>>>(tsT, topkBuf, pairs);
        reduce_k<<<1, 1024, 0, stream>>>(pairs, msep, out);
    } else if (big) {
        float2* tsT = (float2*)(ws + R3_OFF_TS);
        transpose_k<<<tg_grid, tg_blk, 0, stream>>>(fc, tg, tsT, msep, acc);
        series_k<<<NSER / WPB, 64 * WPB, 0, stream>>>(tsT, fc, tg, 1, pairs, acc);
        reduce_k<<<1, 1024, 0, stream>>>(pairs, msep, out);
    } else if (mid) {
        float2* tsT = (float2*)(ws + OFF_MSE);
        hipMemsetAsync(d_ws, 0, 64, stream);
        transpose_k<<<tg_grid, tg_blk, 0, stream>>>(fc, tg, tsT, nullptr, acc);
        series_k<<<NSER / WPB, 64 * WPB, 0, stream>>>(tsT, fc, tg, 1, nullptr, acc);
        finalize_k<<<1, 1, 0, stream>>>(acc, out);
    } else {
        hipMemsetAsync(d_ws, 0, 64, stream);
        mse_k<<<1024, 256, 0, stream>>>(fc, tg, acc);
        series_k<<<NSER / WPB, 64 * WPB, 0, stream>>>(nullptr, fc, tg, 0, nullptr, acc);
        finalize_k<<<1, 1, 0, stream>>>(acc, out);
    }
}

// Round 5
// 216.672 us; speedup vs baseline: 3.2453x; 1.0501x over previous
//
#include <hip/hip_runtime.h>
#include <hip/hip_bf16.h>

#define TT 336
#define NF 321
#define NB 64
#define NSER (NB * NF)   // 20544 series
#define WPB 4            // waves (series) per block in patch kernels
#define KP 352           // K padded to multiple of 32 for 16x16x32 MFMA
#define LDA 360          // LDS row stride (ushorts) in psd_k

// transpose grid: 11 x 11 x 64 blocks
#define TGX 11
#define TGY 11
#define NMSEP (TGX * TGY * NB)   // 7744 per-block MSE partials

typedef __attribute__((ext_vector_type(8))) short bf16x8;
typedef __attribute__((ext_vector_type(4))) float f32x4;
typedef unsigned long long ULL;

__device__ __forceinline__ unsigned short f2bf(float v) {
    unsigned x = __float_as_uint(v);
    x += 0x7FFFu + ((x >> 16) & 1u);   // RNE; inputs are finite
    return (unsigned short)(x >> 16);
}

// sorted-3 insert (a0 >= a1 >= a2)
__device__ __forceinline__ void ins3(ULL& a0, ULL& a1, ULL& a2, ULL x) {
    ULL hi = a0 > x ? a0 : x;
    ULL lo = a0 > x ? x : a0;
    a0 = hi;
    ULL hi1 = a1 > lo ? a1 : lo;
    ULL lo1 = a1 > lo ? lo : a1;
    a1 = hi1;
    a2 = a2 > lo1 ? a2 : lo1;
}

// ---------------------------------------------------------------------------
// Twiddle matrix: Wb[n][k], n=2(f-1) -> cos(2pi f k/336), n=2(f-1)+1 -> sin
// (sign of sin irrelevant: only |X|^2 is used). k in [336,352) zero-padded.
// ---------------------------------------------------------------------------
__global__ void twiddle_k(unsigned short* __restrict__ Wb) {
    int n = blockIdx.x;          // 0..335
    int f = (n >> 1) + 1;
    int isSin = n & 1;
    for (int k = threadIdx.x; k < KP; k += blockDim.x) {
        float v = 0.0f;
        if (k < TT) {
            int r = (f * k) % TT;
            double ang = 6.283185307179586476925286766559 * (double)r / 336.0;
            v = isSin ? (float)sin(ang) : (float)cos(ang);
        }
        Wb[(size_t)n * KP + k] = f2bf(v);
    }
}

// ---------------------------------------------------------------------------
// PSD + top-3 via MFMA GEMM. Block = 64 series, 4 waves; wave = 16-series
// stripe x all 336 cols. A: bf16 series tile (LDS). B: twiddle matrix (L2).
// C layout (m89-verified): col=lane&15, row=(lane>>4)*4+reg.
// ---------------------------------------------------------------------------
__global__ __launch_bounds__(256) void psd_k(const float* __restrict__ tgO,
                                             const unsigned short* __restrict__ Wb,
                                             uint4* __restrict__ topk) {
    __shared__ __align__(16) unsigned short sA[64][LDA];
    const int tid = threadIdx.x;
    const int serBase = blockIdx.x * 64;

    // ---- stage A-tile (wave = 64 consecutive features at fixed t: coalesced) ----
    {
        int f_l = tid & 63, tch = tid >> 6;
        int ser = serBase + f_l;
        int bb = ser / NF, ff = ser - bb * NF;
        const float* base = tgO + (size_t)bb * TT * NF + ff;
        int t0 = tch * 84;
        for (int i = 0; i < 84; i++)
            sA[f_l][t0 + i] = f2bf(base[(size_t)(t0 + i) * NF]);
    }
    for (int idx = tid; idx < 64 * 16; idx += 256)
        sA[idx >> 4][TT + (idx & 15)] = 0;
    __syncthreads();

    const int wave = tid >> 6, lane = tid & 63;
    const int quad = lane >> 4, c = lane & 15;
    const unsigned short* aRow = &sA[wave * 16 + c][quad * 8];
    const unsigned short* bBase = Wb + (size_t)c * KP + quad * 8;

    f32x4 acc[21];
#pragma unroll
    for (int nt = 0; nt < 21; nt++) acc[nt] = (f32x4){0.f, 0.f, 0.f, 0.f};
    for (int ks = 0; ks < 11; ks++) {
        bf16x8 a = *(const bf16x8*)(aRow + ks * 32);
#pragma unroll
        for (int nt = 0; nt < 21; nt++) {
            bf16x8 b = *(const bf16x8*)(bBase + (size_t)nt * 16 * KP + ks * 32);
            acc[nt] = __builtin_amdgcn_mfma_f32_16x16x32_bf16(a, b, acc[nt], 0, 0, 0);
        }
    }

    // ---- PSD (pair adjacent cos/sin cols) + per-reg running top-3 ----
    ULL t0k[4] = {0, 0, 0, 0}, t1k[4] = {0, 0, 0, 0}, t2k[4] = {0, 0, 0, 0};
#pragma unroll
    for (int nt = 0; nt < 21; nt++) {
        unsigned fidx = (unsigned)(((nt * 16 + c) >> 1) + 1);
        unsigned ftag = 0xFFFFFFFFu - fidx;
        bool odd = (c & 1) != 0;
#pragma unroll
        for (int r = 0; r < 4; r++) {
            float v = acc[nt][r];
            float p = v * v;
            p += __shfl_xor(p, 1, 64);
            ULL key = odd ? 0ull
                          : (((ULL)__float_as_uint(p) << 32) | (ULL)ftag);
            ins3(t0k[r], t1k[r], t2k[r], key);
        }
    }
#pragma unroll
    for (int m = 2; m <= 8; m <<= 1) {
#pragma unroll
        for (int r = 0; r < 4; r++) {
            ULL b0 = __shfl_xor(t0k[r], m, 64);
            ULL b1 = __shfl_xor(t1k[r], m, 64);
            ULL b2 = __shfl_xor(t2k[r], m, 64);
            ins3(t0k[r], t1k[r], t2k[r], b0);
            ins3(t0k[r], t1k[r], t2k[r], b1);
            ins3(t0k[r], t1k[r], t2k[r], b2);
        }
    }
    if (c == 0) {
#pragma unroll
        for (int r = 0; r < 4; r++) {
            unsigned f0 = 0xFFFFFFFFu - (unsigned)(t0k[r] & 0xFFFFFFFFull);
            unsigned f1 = 0xFFFFFFFFu - (unsigned)(t1k[r] & 0xFFFFFFFFull);
            unsigned f2 = 0xFFFFFFFFu - (unsigned)(t2k[r] & 0xFFFFFFFFull);
            topk[serBase + wave * 16 + quad * 4 + r] = make_uint4(f0, f1, f2, 0u);
        }
    }
}

// ---------------------------------------------------------------------------
// Kernel 1: transpose [B, T, F] -> interleaved float2{tg,fc}[B*F][T], fused MSE.
// ---------------------------------------------------------------------------
__global__ __launch_bounds__(256) void transpose_k(const float* __restrict__ fc,
                                                   const float* __restrict__ tg,
                                                   float2* __restrict__ out,
                                                   double* __restrict__ msep,
                                                   double* __restrict__ acc) {
    __shared__ float ta[32][33];
    __shared__ float tb[32][33];
    __shared__ double wacc[4];
    const int b = blockIdx.z;
    const int t0 = blockIdx.x * 32, f0 = blockIdx.y * 32;
    const int tx = threadIdx.x, ty = threadIdx.y;   // block (32, 8)
    const size_t base = (size_t)b * TT * NF;
    double ms = 0.0;
#pragma unroll
    for (int k = 0; k < 4; k++) {
        int t = t0 + ty + 8 * k, f = f0 + tx;
        if (t < TT && f < NF) {
            float a = tg[base + (size_t)t * NF + f];
            float c = fc[base + (size_t)t * NF + f];
            ta[ty + 8 * k][tx] = a;
            tb[ty + 8 * k][tx] = c;
            double d = (double)a - (double)c;
            ms += d * d;
        }
    }
    __syncthreads();
#pragma unroll
    for (int k = 0; k < 4; k++) {
        int f = f0 + ty + 8 * k, t = t0 + tx;
        if (t < TT && f < NF) {
            out[((size_t)b * NF + f) * TT + t] =
                make_float2(ta[tx][ty + 8 * k], tb[tx][ty + 8 * k]);
        }
    }
    for (int off = 32; off; off >>= 1) ms += __shfl_down(ms, off, 64);
    int flat = ty * 32 + tx;
    int lane = flat & 63, wid = flat >> 6;
    if (lane == 0) wacc[wid] = ms;
    __syncthreads();
    if (flat == 0) {
        double tot = wacc[0] + wacc[1] + wacc[2] + wacc[3];
        if (msep) {
            int blk = (blockIdx.z * TGY + blockIdx.y) * TGX + blockIdx.x;
            msep[blk] = tot;
        } else {
            atomicAdd(&acc[0], tot);
        }
    }
}

// ---------------------------------------------------------------------------
__global__ void mse_k(const float* __restrict__ fc, const float* __restrict__ tg,
                      double* __restrict__ acc) {
    const size_t N4 = (size_t)NB * TT * NF / 4;
    const float4* a4 = (const float4*)fc;
    const float4* b4 = (const float4*)tg;
    double s = 0.0;
    for (size_t i = (size_t)blockIdx.x * blockDim.x + threadIdx.x; i < N4;
         i += (size_t)gridDim.x * blockDim.x) {
        float4 a = a4[i], b = b4[i];
        double d0 = (double)a.x - (double)b.x;
        double d1 = (double)a.y - (double)b.y;
        double d2 = (double)a.z - (double)b.z;
        double d3 = (double)a.w - (double)b.w;
        s += d0 * d0 + d1 * d1 + d2 * d2 + d3 * d3;
    }
    for (int off = 32; off; off >>= 1) s += __shfl_down(s, off, 64);
    __shared__ double wsum[4];
    int flat = threadIdx.x;
    int lane = flat & 63, wid = flat >> 6;
    if (lane == 0) wsum[wid] = s;
    __syncthreads();
    if (flat == 0) atomicAdd(&acc[0], wsum[0] + wsum[1] + wsum[2] + wsum[3]);
}

// ---------------------------------------------------------------------------
__device__ __forceinline__ double patch_loss(double S1, double S2, double S3,
                                             double S4, double S5, double nn) {
    double mt = S1 / nn, mf = S2 / nn;
    double tvs = S3 - nn * mt * mt; tvs = tvs > 0.0 ? tvs : 0.0;
    double fvs = S4 - nn * mf * mf; fvs = fvs > 0.0 ? fvs : 0.0;
    double num = S5 - nn * mt * mf;
    double corr = num / (sqrt(tvs * fvs) + 1e-8);
    double closs = 1.0 - fabs(corr);
    double tvar = tvs / (nn - 1.0), fvar = fvs / (nn - 1.0);
    double vloss = fabs(tvar - fvar) / (tvar + 1e-8);
    double mloss = fabs(mt - mf) / (fabs(mt) + 1e-8);
    return closs + vloss + mloss;
}

// ---------------------------------------------------------------------------
// Patch enumeration helpers (validity + dedup) shared by both paths.
// ---------------------------------------------------------------------------
struct PatchCfg {
    int P[3], nseg[3], rs[3];
    bool vp[3], hr[3];
};

__device__ __forceinline__ void make_cfg(int fr0, int fr1, int fr2, PatchCfg& c) {
    c.P[0] = TT / fr0; c.P[1] = TT / fr1; c.P[2] = TT / fr2;
    c.vp[0] = (c.P[0] >= 5);
    c.vp[1] = (c.P[1] >= 5) && (c.P[1] != c.P[0]);
    c.vp[2] = (c.P[2] >= 5) && (c.P[2] != c.P[0]) && (c.P[2] != c.P[1]);
#pragma unroll
    for (int q = 0; q < 3; q++) {
        c.nseg[q] = TT / c.P[q];
        c.rs[q] = c.nseg[q] * c.P[q];
        c.hr[q] = c.vp[q] && ((TT - c.rs[q]) >= 5);
    }
}

// slot i in [0,204) -> (s,e,kept) with dedup against earlier periods
__device__ __forceinline__ bool slot_patch(const PatchCfg& c, int i, int& s, int& e) {
    bool kept = false;
    s = 0; e = 0;
    if (i < 204) {
        int k = (i >= 136) ? 2 : ((i >= 68) ? 1 : 0);
        int si = i - k * 68;
        if (c.vp[k]) {
            if (si < c.nseg[k]) { s = c.P[k] * si; e = s + c.P[k]; kept = true; }
            else if (si == c.nseg[k] && c.hr[k]) { s = c.rs[k]; e = TT; kept = true; }
            if (kept) {
#pragma unroll
                for (int j = 0; j < 2; j++) {
                    if (j < k && c.vp[j]) {
                        bool dup = (s == c.rs[j]) && (e == TT) && c.hr[j];
                        int len = e - s;
                        if (len == c.P[j] && (s % c.P[j]) == 0 && (s / c.P[j]) < c.nseg[j]) dup = true;
                        if (dup) kept = false;
                    }
                }
            }
        }
    }
    return kept;
}

// ---------------------------------------------------------------------------
// Kernel: patch stats via register chunk-prefix scan. 4 waves/block,
// 1 series/wave. O(1) per patch (2 shfl-gathers + <=5 edge elements each).
// ---------------------------------------------------------------------------
__global__ __launch_bounds__(256) void patch_k(const float2* __restrict__ tsG,
                                               const uint4* __restrict__ topk,
                                               double2* __restrict__ pairs) {
    const int w = threadIdx.x >> 6, lane = threadIdx.x & 63;
    const int ser = blockIdx.x * WPB + w;
    __shared__ float2 ts[WPB][TT];

    // ---- load 6 contiguous elements per lane (lanes 0..55), 3x float4 ----
    const float2* sp = tsG + (size_t)ser * TT;
    double p1 = 0, p2 = 0, p3 = 0, p4s = 0, p5 = 0;   // chunk sums -> prefixes
    if (lane < 56) {
        const float4* q4 = (const float4*)(sp + 6 * lane);
        float4 va = q4[0], vb = q4[1], vc = q4[2];
        float2 loc[6] = {make_float2(va.x, va.y), make_float2(va.z, va.w),
                         make_float2(vb.x, vb.y), make_float2(vb.z, vb.w),
                         make_float2(vc.x, vc.y), make_float2(vc.z, vc.w)};
#pragma unroll
        for (int i = 0; i < 6; i++) {
            ts[w][6 * lane + i] = loc[i];
            double a = loc[i].x, b = loc[i].y;
            p1 += a; p2 += b; p3 += a * a; p4s += b * b; p5 += a * b;
        }
    }
    __syncthreads();

    // ---- inclusive scan over 64 lanes (chunk granularity = 6 elements) ----
#pragma unroll
    for (int off = 1; off < 64; off <<= 1) {
        double y1 = __shfl_up(p1, off, 64);
        double y2 = __shfl_up(p2, off, 64);
        double y3 = __shfl_up(p3, off, 64);
        double y4 = __shfl_up(p4s, off, 64);
        double y5 = __shfl_up(p5, off, 64);
        if (lane >= off) { p1 += y1; p2 += y2; p3 += y3; p4s += y4; p5 += y5; }
    }

    // PS(b): 5 prefix sums over [0,b), b in [0,336]
    auto PS = [&](int b, double& g1, double& g2, double& g3, double& g4, double& g5) {
        int q = b / 6, r = b - 6 * q;
        int src = q - 1;
        bool hasq = (q > 0);
        double a1 = __shfl(p1, hasq ? src : 0, 64);
        double a2 = __shfl(p2, hasq ? src : 0, 64);
        double a3 = __shfl(p3, hasq ? src : 0, 64);
        double a4 = __shfl(p4s, hasq ? src : 0, 64);
        double a5 = __shfl(p5, hasq ? src : 0, 64);
        g1 = hasq ? a1 : 0.0; g2 = hasq ? a2 : 0.0; g3 = hasq ? a3 : 0.0;
        g4 = hasq ? a4 : 0.0; g5 = hasq ? a5 : 0.0;
#pragma unroll
        for (int i = 0; i < 5; i++) {
            if (i < r) {
                float2 v = ts[w][6 * q + i];
                double a = v.x, bb = v.y;
                g1 += a; g2 += bb; g3 += a * a; g4 += bb * bb; g5 += a * bb;
            }
        }
    };

    uint4 tk = topk[ser];
    PatchCfg cfg;
    make_cfg((int)tk.x, (int)tk.y, (int)tk.z, cfg);

    double lsum = 0.0, lcnt = 0.0;
    unsigned long long anyMask = 0ull;
#pragma unroll
    for (int rI = 0; rI < 4; rI++) {
        int s, e;
        bool kept = slot_patch(cfg, lane + 64 * rI, s, e);
        anyMask |= __ballot(kept);
        // all lanes execute PS (shfl needs full wave); dummies use (0,0)
        int su = kept ? s : 0, eu = kept ? e : 0;
        double s1, s2, s3, s4, s5, e1, e2, e3, e4, e5;
        PS(su, s1, s2, s3, s4, s5);
        PS(eu, e1, e2, e3, e4, e5);
        if (kept) {
            lsum += patch_loss(e1 - s1, e2 - s2, e3 - s3, e4 - s4, e5 - s5,
                               (double)(e - s));
            lcnt += 1.0;
        }
    }

    // ---- fallback whole-series patch: PS(336) = prefix at lane 55 ----
    if (anyMask == 0ull) {
        double f1 = __shfl(p1, 55, 64), f2 = __shfl(p2, 55, 64);
        double f3 = __shfl(p3, 55, 64), f4 = __shfl(p4s, 55, 64);
        double f5 = __shfl(p5, 55, 64);
        if (lane == 0) {
            lsum += patch_loss(f1, f2, f3, f4, f5, (double)TT);
            lcnt += 1.0;
        }
    }

    for (int off = 32; off; off >>= 1) {
        lsum += __shfl_down(lsum, off, 64);
        lcnt += __shfl_down(lcnt, off, 64);
    }
    if (lane == 0) pairs[ser] = make_double2(lsum, lcnt);
}

// ---------------------------------------------------------------------------
// FALLBACK: self-contained series kernel (VALU DFT + topk + serial patches).
// ---------------------------------------------------------------------------
__device__ __forceinline__ void patch_body(const float2* tsw, int lane,
                                           int fr0, int fr1, int fr2,
                                           double& lsum, double& lcnt) {
    PatchCfg cfg;
    make_cfg(fr0, fr1, fr2, cfg);
    unsigned long long anyMask = 0ull;
#pragma unroll
    for (int rI = 0; rI < 4; rI++) {
        int s, e;
        bool kept = slot_patch(cfg, lane + 64 * rI, s, e);
        anyMask |= __ballot(kept);
        if (kept) {
            double S1 = 0, S2 = 0, S3 = 0, S4 = 0, S5 = 0;
            for (int t = s; t < e; t++) {
                float2 v = tsw[t];
                double a = (double)v.x, b = (double)v.y;
                S1 += a; S2 += b;
                S3 += a * a; S4 += b * b; S5 += a * b;
            }
            lsum += patch_loss(S1, S2, S3, S4, S5, (double)(e - s));
            lcnt += 1.0;
        }
    }
    if (anyMask == 0ull) {
        double S1 = 0, S2 = 0, S3 = 0, S4 = 0, S5 = 0;
        for (int t = lane; t < TT; t += 64) {
            float2 v = tsw[t];
            double a = (double)v.x, b = (double)v.y;
            S1 += a; S2 += b;
            S3 += a * a; S4 += b * b; S5 += a * b;
        }
        for (int off = 32; off; off >>= 1) {
            S1 += __shfl_down(S1, off, 64);
            S2 += __shfl_down(S2, off, 64);
            S3 += __shfl_down(S3, off, 64);
            S4 += __shfl_down(S4, off, 64);
            S5 += __shfl_down(S5, off, 64);
        }
        if (lane == 0) {
            lsum += patch_loss(S1, S2, S3, S4, S5, (double)TT);
            lcnt += 1.0;
        }
    }
}

__global__ __launch_bounds__(256, 6) void series_k(const float2* __restrict__ tsG,
                                                   const float* __restrict__ fcG,
                                                   const float* __restrict__ tgG,
                                                   int transposed,
                                                   double2* __restrict__ pairs,
                                                   double* __restrict__ acc) {
    const int w = threadIdx.x >> 6, lane = threadIdx.x & 63;
    const int ser = blockIdx.x * WPB + w;
    __shared__ float2 ts[WPB][TT];
    __shared__ float4 zb[WPB][84];

    if (transposed) {
        const float2* sp = tsG + (size_t)ser * TT;
        for (int t = lane; t < TT; t += 64) ts[w][t] = sp[t];
    } else {
        int b = ser / NF, f = ser - b * NF;
        const float* tp = tgG + (size_t)b * TT * NF + f;
        const float* fp = fcG + (size_t)b * TT * NF + f;
        for (int t = lane; t < TT; t += 64)
            ts[w][t] = make_float2(tp[(size_t)t * NF], fp[(size_t)t * NF]);
    }
    __syncthreads();

    for (int t = lane; t < 84; t += 64) {
        float x0 = ts[w][t].x, x1 = ts[w][t + 84].x;
        float x2 = ts[w][t + 168].x, x3 = ts[w][t + 252].x;
        float a = x0 + x2, b2 = x1 + x3, c = x0 - x2, d = x1 - x3;
        zb[w][t] = make_float4(a + b2, a - b2, c, d);
    }
    __syncthreads();

    const double TWOPI = 6.283185307179586476925286766559;
    int fb[3] = {1 + lane, 65 + lane, 129 + lane};
    float cc[3], sn[3], re[3], im[3], cd[3], sd[3], sgn[3];
    int selA[3];
#pragma unroll
    for (int q = 0; q < 3; q++) {
        int f = fb[q], cls = f & 3;
        double dl = (double)f * (TWOPI / 336.0);
        cd[q] = (float)cos(dl);
        sd[q] = (float)sin(dl);
        cc[q] = 1.0f; sn[q] = 0.0f; re[q] = 0.0f; im[q] = 0.0f;
        sgn[q] = (cls == 1) ? -1.0f : ((cls == 3) ? 1.0f : 0.0f);
        selA[q] = (cls == 0) ? 0 : ((cls == 2) ? 1 : 2);
    }
    for (int t = 0; t < 84; t++) {
        float4 zv = zb[w][t];
#pragma unroll
        for (int q = 0; q < 3; q++) {
            float zr = (selA[q] == 0) ? zv.x : ((selA[q] == 1) ? zv.y : zv.z);
            float zi = sgn[q] * zv.w;
            re[q] = fmaf(zr, cc[q], re[q]);
            re[q] = fmaf(zi, sn[q], re[q]);
            im[q] = fmaf(zi, cc[q], im[q]);
            im[q] = fmaf(-zr, sn[q], im[q]);
            float nc = fmaf(cc[q], cd[q], -(sn[q] * sd[q]));
            float ns = fmaf(sn[q], cd[q], cc[q] * sd[q]);
            cc[q] = nc; sn[q] = ns;
        }
    }

    ULL k0 = 0, k1 = 0, k2 = 0;
#pragma unroll
    for (int q = 0; q < 3; q++) {
        float a2 = fmaf(re[q], re[q], im[q] * im[q]);
        ULL key = ((ULL)__float_as_uint(a2) << 32) |
                  (ULL)(0xFFFFFFFFu - (unsigned)fb[q]);
        if (fb[q] > 168) key = 0ull;
        ins3(k0, k1, k2, key);
    }
    for (int m = 1; m < 64; m <<= 1) {
        ULL b0 = __shfl_xor(k0, m, 64);
        ULL b1 = __shfl_xor(k1, m, 64);
        ULL b2 = __shfl_xor(k2, m, 64);
        ins3(k0, k1, k2, b0); ins3(k0, k1, k2, b1); ins3(k0, k1, k2, b2);
    }

    int fr0 = (int)(0xFFFFFFFFu - (unsigned)(k0 & 0xFFFFFFFFull));
    int fr1 = (int)(0xFFFFFFFFu - (unsigned)(k1 & 0xFFFFFFFFull));
    int fr2 = (int)(0xFFFFFFFFu - (unsigned)(k2 & 0xFFFFFFFFull));

    double lsum = 0.0, lcnt = 0.0;
    patch_body(&ts[w][0], lane, fr0, fr1, fr2, lsum, lcnt);

    for (int off = 32; off; off >>= 1) {
        lsum += __shfl_down(lsum, off, 64);
        lcnt += __shfl_down(lcnt, off, 64);
    }
    if (lane == 0) {
        if (pairs) {
            pairs[ser] = make_double2(lsum, lcnt);
        } else {
            atomicAdd(&acc[1], lsum);
            atomicAdd(&acc[2], lcnt);
        }
    }
}

// ---------------------------------------------------------------------------
__global__ __launch_bounds__(1024) void reduce_k(const double2* __restrict__ pairs,
                                                 const double* __restrict__ msep,
                                                 float* __restrict__ out) {
    const int tid = threadIdx.x;
    double ls = 0.0, lc = 0.0, ms = 0.0;
    for (int i = tid; i < NSER; i += 1024) {
        double2 p = pairs[i];
        ls += p.x; lc += p.y;
    }
    for (int i = tid; i < NMSEP; i += 1024) ms += msep[i];
    for (int off = 32; off; off >>= 1) {
        ls += __shfl_down(ls, off, 64);
        lc += __shfl_down(lc, off, 64);
        ms += __shfl_down(ms, off, 64);
    }
    __shared__ double sl[16], sc[16], sm[16];
    int lane = tid & 63, wid = tid >> 6;
    if (lane == 0) { sl[wid] = ls; sc[wid] = lc; sm[wid] = ms; }
    __syncthreads();
    if (tid == 0) {
        double L = 0, C = 0, M = 0;
        for (int i = 0; i < 16; i++) { L += sl[i]; C += sc[i]; M += sm[i]; }
        double mse = M / (double)((size_t)NB * TT * NF);
        double avg = (C > 0.0) ? (L / C) : 0.0;
        out[0] = (float)(0.5 * mse + 0.5 * avg);
    }
}

__global__ void finalize_k(const double* __restrict__ acc, float* __restrict__ out) {
    double mse = acc[0] / (double)((size_t)NB * TT * NF);
    double avg = (acc[2] > 0.0) ? (acc[1] / acc[2]) : 0.0;
    out[0] = (float)(0.5 * mse + 0.5 * avg);
}

// ---------------------------------------------------------------------------
extern "C" void kernel_launch(void* const* d_in, const int* in_sizes, int n_in,
                              void* d_out, int out_size, void* d_ws, size_t ws_size,
                              hipStream_t stream) {
    const float* fc = (const float*)d_in[0];   // forecast
    const float* tg = (const float*)d_in[1];   // target
    float* out = (float*)d_out;
    char* ws = (char*)d_ws;
    double* acc = (double*)ws;

    // layout: [0,64) acc | msep | pairs | topk | Wb | tsT
    const size_t OFF_MSE = 64;
    const size_t OFF_PAIR = OFF_MSE + (size_t)NMSEP * sizeof(double);        // 62016
    const size_t OFF_TOP = OFF_PAIR + (size_t)NSER * sizeof(double2);        // 390720
    const size_t OFF_W = OFF_TOP + (size_t)NSER * sizeof(uint4);             // 719424
    const size_t OFF_TS = OFF_W + (size_t)TT * KP * sizeof(unsigned short);  // 955968
    const size_t bytesT = (size_t)NSER * TT * sizeof(float2);
    const bool big2 = (ws_size >= OFF_TS + bytesT);
    const size_t R3_OFF_TS = OFF_PAIR + (size_t)NSER * sizeof(double2);
    const bool big = !big2 && (ws_size >= R3_OFF_TS + bytesT);
    const bool mid = !big2 && !big && (ws_size >= OFF_MSE + bytesT);

    double* msep = (double*)(ws + OFF_MSE);
    double2* pairs = (double2*)(ws + OFF_PAIR);
    uint4* topkBuf = (uint4*)(ws + OFF_TOP);
    unsigned short* Wb = (unsigned short*)(ws + OFF_W);

    dim3 tg_grid(TGX, TGY, NB);
    dim3 tg_blk(32, 8);

    if (big2) {
        float2* tsT = (float2*)(ws + OFF_TS);
        twiddle_k<<<TT, 128, 0, stream>>>(Wb);
        transpose_k<<<tg_grid, tg_blk, 0, stream>>>(fc, tg, tsT, msep, acc);
        psd_k<<<NSER / 64, 256, 0, stream>>>(tg, Wb, topkBuf);
        patch_k<<<NSER / WPB, 64 * WPB, 0, stream>>>(tsT, topkBuf, pairs);
        reduce_k<<<1, 1024, 0, stream>>>(pairs, msep, out);
    } else if (big) {
        float2* tsT = (float2*)(ws + R3_OFF_TS);
        transpose_k<<<tg_grid, tg_blk, 0, stream>>>(fc, tg, tsT, msep, acc);
        series_k<<<NSER / WPB, 64 * WPB, 0, stream>>>(tsT, fc, tg, 1, pairs, acc);
        reduce_k<<<1, 1024, 0, stream>>>(pairs, msep, out);
    } else if (mid) {
        float2* tsT = (float2*)(ws + OFF_MSE);
        hipMemsetAsync(d_ws, 0, 64, stream);
        transpose_k<<<tg_grid, tg_blk, 0, stream>>>(fc, tg, tsT, nullptr, acc);
        series_k<<<NSER / WPB, 64 * WPB, 0, stream>>>(tsT, fc, tg, 1, nullptr, acc);
        finalize_k<<<1, 1, 0, stream>>>(acc, out);
    } else {
        hipMemsetAsync(d_ws, 0, 64, stream);
        mse_k<<<1024, 256, 0, stream>>>(fc, tg, acc);
        series_k<<<NSER / WPB, 64 * WPB, 0, stream>>>(nullptr, fc, tg, 0, nullptr, acc);
        finalize_k<<<1, 1, 0, stream>>>(acc, out);
    }
}

// Round 6
// 202.714 us; speedup vs baseline: 3.4687x; 1.0689x over previous
//
#include <hip/hip_runtime.h>
#include <hip/hip_bf16.h>

#define TT 336
#define NF 321
#define NB 64
#define NSER (NB * NF)   // 20544 series
#define WPB 4            // waves (series) per block in patch kernels
#define KP 352           // K padded to multiple of 32 for 16x16x32 MFMA
#define LDA 360          // LDS row stride (ushorts) in psd_k
#define SPB 16           // series per block in psd_k (grid = 1284)

// transpose grid: 11 x 11 x 64 blocks
#define TGX 11
#define TGY 11
#define NMSEP (TGX * TGY * NB)   // 7744 per-block MSE partials

typedef __attribute__((ext_vector_type(8))) short bf16x8;
typedef __attribute__((ext_vector_type(4))) float f32x4;
typedef unsigned long long ULL;

__device__ __forceinline__ unsigned short f2bf(float v) {
    unsigned x = __float_as_uint(v);
    x += 0x7FFFu + ((x >> 16) & 1u);   // RNE; inputs are finite
    return (unsigned short)(x >> 16);
}

// sorted-3 insert (a0 >= a1 >= a2)
__device__ __forceinline__ void ins3(ULL& a0, ULL& a1, ULL& a2, ULL x) {
    ULL hi = a0 > x ? a0 : x;
    ULL lo = a0 > x ? x : a0;
    a0 = hi;
    ULL hi1 = a1 > lo ? a1 : lo;
    ULL lo1 = a1 > lo ? lo : a1;
    a1 = hi1;
    a2 = a2 > lo1 ? a2 : lo1;
}

// ---------------------------------------------------------------------------
// Twiddle matrix: Wb[n][k], n=2(f-1) -> cos(2pi f k/336), n=2(f-1)+1 -> sin
// (sign of sin irrelevant: only |X|^2 is used). k in [336,352) zero-padded.
// ---------------------------------------------------------------------------
__global__ void twiddle_k(unsigned short* __restrict__ Wb) {
    int n = blockIdx.x;          // 0..335
    int f = (n >> 1) + 1;
    int isSin = n & 1;
    for (int k = threadIdx.x; k < KP; k += blockDim.x) {
        float v = 0.0f;
        if (k < TT) {
            int r = (f * k) % TT;
            double ang = 6.283185307179586476925286766559 * (double)r / 336.0;
            v = isSin ? (float)sin(ang) : (float)cos(ang);
        }
        Wb[(size_t)n * KP + k] = f2bf(v);
    }
}

// ---------------------------------------------------------------------------
// PSD + top-3 via MFMA GEMM. Block = 16 series, 4 waves split the 21
// nt-tiles (5/5/5/6) over a shared A-tile; per-wave top-3 then LDS merge
// (disjoint freq ranges -> exact). Grid = 1284 blocks for latency hiding.
// C layout (m89-verified): col=lane&15 (freq), row=(lane>>4)*4+reg (series).
// ---------------------------------------------------------------------------
__global__ __launch_bounds__(256) void psd_k(const float* __restrict__ tgO,
                                             const unsigned short* __restrict__ Wb,
                                             uint4* __restrict__ topk) {
    __shared__ __align__(16) unsigned short sA[SPB][LDA];
    __shared__ ULL tk3[4][SPB][3];
    const int tid = threadIdx.x;
    const int serBase = blockIdx.x * SPB;

    // ---- stage A-tile: 16 lanes = 16 consecutive features (64B rows) ----
    {
        int f_l = tid & 15, tch = tid >> 4;   // 16 t-chunks of 21
        int ser = serBase + f_l;
        int bb = ser / NF, ff = ser - bb * NF;
        const float* base = tgO + (size_t)bb * TT * NF + ff;
        int t0 = tch * 21;
#pragma unroll 3
        for (int i = 0; i < 21; i++)
            sA[f_l][t0 + i] = f2bf(base[(size_t)(t0 + i) * NF]);
    }
    if (tid < SPB * 16) sA[tid >> 4][TT + (tid & 15)] = 0;   // K padding
    __syncthreads();

    const int wave = tid >> 6, lane = tid & 63;
    const int quad = lane >> 4, c = lane & 15;
    const unsigned short* aRow = &sA[c][quad * 8];   // A[m=c][k=quad*8+j]
    const int ntStart = wave * 5;
    const int ntEnd = (wave == 3) ? 21 : ntStart + 5;

    ULL t0k[4] = {0, 0, 0, 0}, t1k[4] = {0, 0, 0, 0}, t2k[4] = {0, 0, 0, 0};
    for (int nt = ntStart; nt < ntEnd; nt++) {
        const unsigned short* bRow = Wb + (size_t)(nt * 16 + c) * KP + quad * 8;
        f32x4 acc = (f32x4){0.f, 0.f, 0.f, 0.f};
#pragma unroll
        for (int ks = 0; ks < 11; ks++) {
            bf16x8 a = *(const bf16x8*)(aRow + ks * 32);
            bf16x8 b = *(const bf16x8*)(bRow + ks * 32);
            acc = __builtin_amdgcn_mfma_f32_16x16x32_bf16(a, b, acc, 0, 0, 0);
        }
        int n = nt * 16 + c;
        unsigned fidx = (unsigned)((n >> 1) + 1);
        unsigned ftag = 0xFFFFFFFFu - fidx;
        bool odd = (n & 1) != 0;
#pragma unroll
        for (int r = 0; r < 4; r++) {
            float v = acc[r];
            float p = v * v;
            p += __shfl_xor(p, 1, 64);            // pair cos/sin columns
            ULL key = odd ? 0ull
                          : (((ULL)__float_as_uint(p) << 32) | (ULL)ftag);
            ins3(t0k[r], t1k[r], t2k[r], key);
        }
    }
    // merge across the 8 even-c lanes within each quad
#pragma unroll
    for (int m = 2; m <= 8; m <<= 1) {
#pragma unroll
        for (int r = 0; r < 4; r++) {
            ULL b0 = __shfl_xor(t0k[r], m, 64);
            ULL b1 = __shfl_xor(t1k[r], m, 64);
            ULL b2 = __shfl_xor(t2k[r], m, 64);
            ins3(t0k[r], t1k[r], t2k[r], b0);
            ins3(t0k[r], t1k[r], t2k[r], b1);
            ins3(t0k[r], t1k[r], t2k[r], b2);
        }
    }
    if (c == 0) {
#pragma unroll
        for (int r = 0; r < 4; r++) {
            int s = quad * 4 + r;
            tk3[wave][s][0] = t0k[r];
            tk3[wave][s][1] = t1k[r];
            tk3[wave][s][2] = t2k[r];
        }
    }
    __syncthreads();
    // cross-wave merge: one thread per series
    if (tid < SPB) {
        ULL k0 = 0, k1 = 0, k2 = 0;
#pragma unroll
        for (int wv = 0; wv < 4; wv++) {
#pragma unroll
            for (int j = 0; j < 3; j++) ins3(k0, k1, k2, tk3[wv][tid][j]);
        }
        unsigned f0 = 0xFFFFFFFFu - (unsigned)(k0 & 0xFFFFFFFFull);
        unsigned f1 = 0xFFFFFFFFu - (unsigned)(k1 & 0xFFFFFFFFull);
        unsigned f2 = 0xFFFFFFFFu - (unsigned)(k2 & 0xFFFFFFFFull);
        topk[serBase + tid] = make_uint4(f0, f1, f2, 0u);
    }
}

// ---------------------------------------------------------------------------
// Kernel 1: transpose [B, T, F] -> interleaved float2{tg,fc}[B*F][T], fused MSE.
// ---------------------------------------------------------------------------
__global__ __launch_bounds__(256) void transpose_k(const float* __restrict__ fc,
                                                   const float* __restrict__ tg,
                                                   float2* __restrict__ out,
                                                   double* __restrict__ msep,
                                                   double* __restrict__ acc) {
    __shared__ float ta[32][33];
    __shared__ float tb[32][33];
    __shared__ double wacc[4];
    const int b = blockIdx.z;
    const int t0 = blockIdx.x * 32, f0 = blockIdx.y * 32;
    const int tx = threadIdx.x, ty = threadIdx.y;   // block (32, 8)
    const size_t base = (size_t)b * TT * NF;
    double ms = 0.0;
#pragma unroll
    for (int k = 0; k < 4; k++) {
        int t = t0 + ty + 8 * k, f = f0 + tx;
        if (t < TT && f < NF) {
            float a = tg[base + (size_t)t * NF + f];
            float c = fc[base + (size_t)t * NF + f];
            ta[ty + 8 * k][tx] = a;
            tb[ty + 8 * k][tx] = c;
            double d = (double)a - (double)c;
            ms += d * d;
        }
    }
    __syncthreads();
#pragma unroll
    for (int k = 0; k < 4; k++) {
        int f = f0 + ty + 8 * k, t = t0 + tx;
        if (t < TT && f < NF) {
            out[((size_t)b * NF + f) * TT + t] =
                make_float2(ta[tx][ty + 8 * k], tb[tx][ty + 8 * k]);
        }
    }
    for (int off = 32; off; off >>= 1) ms += __shfl_down(ms, off, 64);
    int flat = ty * 32 + tx;
    int lane = flat & 63, wid = flat >> 6;
    if (lane == 0) wacc[wid] = ms;
    __syncthreads();
    if (flat == 0) {
        double tot = wacc[0] + wacc[1] + wacc[2] + wacc[3];
        if (msep) {
            int blk = (blockIdx.z * TGY + blockIdx.y) * TGX + blockIdx.x;
            msep[blk] = tot;
        } else {
            atomicAdd(&acc[0], tot);
        }
    }
}

// ---------------------------------------------------------------------------
__global__ void mse_k(const float* __restrict__ fc, const float* __restrict__ tg,
                      double* __restrict__ acc) {
    const size_t N4 = (size_t)NB * TT * NF / 4;
    const float4* a4 = (const float4*)fc;
    const float4* b4 = (const float4*)tg;
    double s = 0.0;
    for (size_t i = (size_t)blockIdx.x * blockDim.x + threadIdx.x; i < N4;
         i += (size_t)gridDim.x * blockDim.x) {
        float4 a = a4[i], b = b4[i];
        double d0 = (double)a.x - (double)b.x;
        double d1 = (double)a.y - (double)b.y;
        double d2 = (double)a.z - (double)b.z;
        double d3 = (double)a.w - (double)b.w;
        s += d0 * d0 + d1 * d1 + d2 * d2 + d3 * d3;
    }
    for (int off = 32; off; off >>= 1) s += __shfl_down(s, off, 64);
    __shared__ double wsum[4];
    int flat = threadIdx.x;
    int lane = flat & 63, wid = flat >> 6;
    if (lane == 0) wsum[wid] = s;
    __syncthreads();
    if (flat == 0) atomicAdd(&acc[0], wsum[0] + wsum[1] + wsum[2] + wsum[3]);
}

// ---------------------------------------------------------------------------
__device__ __forceinline__ double patch_loss(double S1, double S2, double S3,
                                             double S4, double S5, double nn) {
    double mt = S1 / nn, mf = S2 / nn;
    double tvs = S3 - nn * mt * mt; tvs = tvs > 0.0 ? tvs : 0.0;
    double fvs = S4 - nn * mf * mf; fvs = fvs > 0.0 ? fvs : 0.0;
    double num = S5 - nn * mt * mf;
    double corr = num / (sqrt(tvs * fvs) + 1e-8);
    double closs = 1.0 - fabs(corr);
    double tvar = tvs / (nn - 1.0), fvar = fvs / (nn - 1.0);
    double vloss = fabs(tvar - fvar) / (tvar + 1e-8);
    double mloss = fabs(mt - mf) / (fabs(mt) + 1e-8);
    return closs + vloss + mloss;
}

// ---------------------------------------------------------------------------
struct PatchCfg {
    int P[3], nseg[3], rs[3];
    bool vp[3], hr[3];
};

__device__ __forceinline__ void make_cfg(int fr0, int fr1, int fr2, PatchCfg& c) {
    c.P[0] = TT / fr0; c.P[1] = TT / fr1; c.P[2] = TT / fr2;
    c.vp[0] = (c.P[0] >= 5);
    c.vp[1] = (c.P[1] >= 5) && (c.P[1] != c.P[0]);
    c.vp[2] = (c.P[2] >= 5) && (c.P[2] != c.P[0]) && (c.P[2] != c.P[1]);
#pragma unroll
    for (int q = 0; q < 3; q++) {
        c.nseg[q] = TT / c.P[q];
        c.rs[q] = c.nseg[q] * c.P[q];
        c.hr[q] = c.vp[q] && ((TT - c.rs[q]) >= 5);
    }
}

// slot i in [0,204) -> (s,e,kept) with dedup against earlier periods
__device__ __forceinline__ bool slot_patch(const PatchCfg& c, int i, int& s, int& e) {
    bool kept = false;
    s = 0; e = 0;
    if (i < 204) {
        int k = (i >= 136) ? 2 : ((i >= 68) ? 1 : 0);
        int si = i - k * 68;
        if (c.vp[k]) {
            if (si < c.nseg[k]) { s = c.P[k] * si; e = s + c.P[k]; kept = true; }
            else if (si == c.nseg[k] && c.hr[k]) { s = c.rs[k]; e = TT; kept = true; }
            if (kept) {
#pragma unroll
                for (int j = 0; j < 2; j++) {
                    if (j < k && c.vp[j]) {
                        bool dup = (s == c.rs[j]) && (e == TT) && c.hr[j];
                        int len = e - s;
                        if (len == c.P[j] && (s % c.P[j]) == 0 && (s / c.P[j]) < c.nseg[j]) dup = true;
                        if (dup) kept = false;
                    }
                }
            }
        }
    }
    return kept;
}

// ---------------------------------------------------------------------------
// Kernel: patch stats via register chunk-prefix scan. 4 waves/block,
// 1 series/wave. O(1) per patch (2 shfl-gathers + <=5 edge elements each).
// ---------------------------------------------------------------------------
__global__ __launch_bounds__(256) void patch_k(const float2* __restrict__ tsG,
                                               const uint4* __restrict__ topk,
                                               double2* __restrict__ pairs) {
    const int w = threadIdx.x >> 6, lane = threadIdx.x & 63;
    const int ser = blockIdx.x * WPB + w;
    __shared__ float2 ts[WPB][TT];

    // ---- load 6 contiguous elements per lane (lanes 0..55), 3x float4 ----
    const float2* sp = tsG + (size_t)ser * TT;
    double p1 = 0, p2 = 0, p3 = 0, p4s = 0, p5 = 0;   // chunk sums -> prefixes
    if (lane < 56) {
        const float4* q4 = (const float4*)(sp + 6 * lane);
        float4 va = q4[0], vb = q4[1], vc = q4[2];
        float2 loc[6] = {make_float2(va.x, va.y), make_float2(va.z, va.w),
                         make_float2(vb.x, vb.y), make_float2(vb.z, vb.w),
                         make_float2(vc.x, vc.y), make_float2(vc.z, vc.w)};
#pragma unroll
        for (int i = 0; i < 6; i++) {
            ts[w][6 * lane + i] = loc[i];
            double a = loc[i].x, b = loc[i].y;
            p1 += a; p2 += b; p3 += a * a; p4s += b * b; p5 += a * b;
        }
    }
    __syncthreads();

    // ---- inclusive scan over 64 lanes (chunk granularity = 6 elements) ----
#pragma unroll
    for (int off = 1; off < 64; off <<= 1) {
        double y1 = __shfl_up(p1, off, 64);
        double y2 = __shfl_up(p2, off, 64);
        double y3 = __shfl_up(p3, off, 64);
        double y4 = __shfl_up(p4s, off, 64);
        double y5 = __shfl_up(p5, off, 64);
        if (lane >= off) { p1 += y1; p2 += y2; p3 += y3; p4s += y4; p5 += y5; }
    }

    // PS(b): 5 prefix sums over [0,b), b in [0,336]
    auto PS = [&](int b, double& g1, double& g2, double& g3, double& g4, double& g5) {
        int q = b / 6, r = b - 6 * q;
        int src = q - 1;
        bool hasq = (q > 0);
        double a1 = __shfl(p1, hasq ? src : 0, 64);
        double a2 = __shfl(p2, hasq ? src : 0, 64);
        double a3 = __shfl(p3, hasq ? src : 0, 64);
        double a4 = __shfl(p4s, hasq ? src : 0, 64);
        double a5 = __shfl(p5, hasq ? src : 0, 64);
        g1 = hasq ? a1 : 0.0; g2 = hasq ? a2 : 0.0; g3 = hasq ? a3 : 0.0;
        g4 = hasq ? a4 : 0.0; g5 = hasq ? a5 : 0.0;
#pragma unroll
        for (int i = 0; i < 5; i++) {
            if (i < r) {
                float2 v = ts[w][6 * q + i];
                double a = v.x, bb = v.y;
                g1 += a; g2 += bb; g3 += a * a; g4 += bb * bb; g5 += a * bb;
            }
        }
    };

    uint4 tk = topk[ser];
    PatchCfg cfg;
    make_cfg((int)tk.x, (int)tk.y, (int)tk.z, cfg);

    double lsum = 0.0, lcnt = 0.0;
    unsigned long long anyMask = 0ull;
#pragma unroll
    for (int rI = 0; rI < 4; rI++) {
        int s, e;
        bool kept = slot_patch(cfg, lane + 64 * rI, s, e);
        anyMask |= __ballot(kept);
        int su = kept ? s : 0, eu = kept ? e : 0;
        double s1, s2, s3, s4, s5, e1, e2, e3, e4, e5;
        PS(su, s1, s2, s3, s4, s5);
        PS(eu, e1, e2, e3, e4, e5);
        if (kept) {
            lsum += patch_loss(e1 - s1, e2 - s2, e3 - s3, e4 - s4, e5 - s5,
                               (double)(e - s));
            lcnt += 1.0;
        }
    }

    if (anyMask == 0ull) {
        double f1 = __shfl(p1, 55, 64), f2 = __shfl(p2, 55, 64);
        double f3 = __shfl(p3, 55, 64), f4 = __shfl(p4s, 55, 64);
        double f5 = __shfl(p5, 55, 64);
        if (lane == 0) {
            lsum += patch_loss(f1, f2, f3, f4, f5, (double)TT);
            lcnt += 1.0;
        }
    }

    for (int off = 32; off; off >>= 1) {
        lsum += __shfl_down(lsum, off, 64);
        lcnt += __shfl_down(lcnt, off, 64);
    }
    if (lane == 0) pairs[ser] = make_double2(lsum, lcnt);
}

// ---------------------------------------------------------------------------
// FALLBACK: self-contained series kernel (VALU DFT + topk + serial patches).
// ---------------------------------------------------------------------------
__device__ __forceinline__ void patch_body(const float2* tsw, int lane,
                                           int fr0, int fr1, int fr2,
                                           double& lsum, double& lcnt) {
    PatchCfg cfg;
    make_cfg(fr0, fr1, fr2, cfg);
    unsigned long long anyMask = 0ull;
#pragma unroll
    for (int rI = 0; rI < 4; rI++) {
        int s, e;
        bool kept = slot_patch(cfg, lane + 64 * rI, s, e);
        anyMask |= __ballot(kept);
        if (kept) {
            double S1 = 0, S2 = 0, S3 = 0, S4 = 0, S5 = 0;
            for (int t = s; t < e; t++) {
                float2 v = tsw[t];
                double a = (double)v.x, b = (double)v.y;
                S1 += a; S2 += b;
                S3 += a * a; S4 += b * b; S5 += a * b;
            }
            lsum += patch_loss(S1, S2, S3, S4, S5, (double)(e - s));
            lcnt += 1.0;
        }
    }
    if (anyMask == 0ull) {
        double S1 = 0, S2 = 0, S3 = 0, S4 = 0, S5 = 0;
        for (int t = lane; t < TT; t += 64) {
            float2 v = tsw[t];
            double a = (double)v.x, b = (double)v.y;
            S1 += a; S2 += b;
            S3 += a * a; S4 += b * b; S5 += a * b;
        }
        for (int off = 32; off; off >>= 1) {
            S1 += __shfl_down(S1, off, 64);
            S2 += __shfl_down(S2, off, 64);
            S3 += __shfl_down(S3, off, 64);
            S4 += __shfl_down(S4, off, 64);
            S5 += __shfl_down(S5, off, 64);
        }
        if (lane == 0) {
            lsum += patch_loss(S1, S2, S3, S4, S5, (double)TT);
            lcnt += 1.0;
        }
    }
}

__global__ __launch_bounds__(256, 6) void series_k(const float2* __restrict__ tsG,
                                                   const float* __restrict__ fcG,
                                                   const float* __restrict__ tgG,
                                                   int transposed,
                                                   double2* __restrict__ pairs,
                                                   double* __restrict__ acc) {
    const int w = threadIdx.x >> 6, lane = threadIdx.x & 63;
    const int ser = blockIdx.x * WPB + w;
    __shared__ float2 ts[WPB][TT];
    __shared__ float4 zb[WPB][84];

    if (transposed) {
        const float2* sp = tsG + (size_t)ser * TT;
        for (int t = lane; t < TT; t += 64) ts[w][t] = sp[t];
    } else {
        int b = ser / NF, f = ser - b * NF;
        const float* tp = tgG + (size_t)b * TT * NF + f;
        const float* fp = fcG + (size_t)b * TT * NF + f;
        for (int t = lane; t < TT; t += 64)
            ts[w][t] = make_float2(tp[(size_t)t * NF], fp[(size_t)t * NF]);
    }
    __syncthreads();

    for (int t = lane; t < 84; t += 64) {
        float x0 = ts[w][t].x, x1 = ts[w][t + 84].x;
        float x2 = ts[w][t + 168].x, x3 = ts[w][t + 252].x;
        float a = x0 + x2, b2 = x1 + x3, c = x0 - x2, d = x1 - x3;
        zb[w][t] = make_float4(a + b2, a - b2, c, d);
    }
    __syncthreads();

    const double TWOPI = 6.283185307179586476925286766559;
    int fb[3] = {1 + lane, 65 + lane, 129 + lane};
    float cc[3], sn[3], re[3], im[3], cd[3], sd[3], sgn[3];
    int selA[3];
#pragma unroll
    for (int q = 0; q < 3; q++) {
        int f = fb[q], cls = f & 3;
        double dl = (double)f * (TWOPI / 336.0);
        cd[q] = (float)cos(dl);
        sd[q] = (float)sin(dl);
        cc[q] = 1.0f; sn[q] = 0.0f; re[q] = 0.0f; im[q] = 0.0f;
        sgn[q] = (cls == 1) ? -1.0f : ((cls == 3) ? 1.0f : 0.0f);
        selA[q] = (cls == 0) ? 0 : ((cls == 2) ? 1 : 2);
    }
    for (int t = 0; t < 84; t++) {
        float4 zv = zb[w][t];
#pragma unroll
        for (int q = 0; q < 3; q++) {
            float zr = (selA[q] == 0) ? zv.x : ((selA[q] == 1) ? zv.y : zv.z);
            float zi = sgn[q] * zv.w;
            re[q] = fmaf(zr, cc[q], re[q]);
            re[q] = fmaf(zi, sn[q], re[q]);
            im[q] = fmaf(zi, cc[q], im[q]);
            im[q] = fmaf(-zr, sn[q], im[q]);
            float nc = fmaf(cc[q], cd[q], -(sn[q] * sd[q]));
            float ns = fmaf(sn[q], cd[q], cc[q] * sd[q]);
            cc[q] = nc; sn[q] = ns;
        }
    }

    ULL k0 = 0, k1 = 0, k2 = 0;
#pragma unroll
    for (int q = 0; q < 3; q++) {
        float a2 = fmaf(re[q], re[q], im[q] * im[q]);
        ULL key = ((ULL)__float_as_uint(a2) << 32) |
                  (ULL)(0xFFFFFFFFu - (unsigned)fb[q]);
        if (fb[q] > 168) key = 0ull;
        ins3(k0, k1, k2, key);
    }
    for (int m = 1; m < 64; m <<= 1) {
        ULL b0 = __shfl_xor(k0, m, 64);
        ULL b1 = __shfl_xor(k1, m, 64);
        ULL b2 = __shfl_xor(k2, m, 64);
        ins3(k0, k1, k2, b0); ins3(k0, k1, k2, b1); ins3(k0, k1, k2, b2);
    }

    int fr0 = (int)(0xFFFFFFFFu - (unsigned)(k0 & 0xFFFFFFFFull));
    int fr1 = (int)(0xFFFFFFFFu - (unsigned)(k1 & 0xFFFFFFFFull));
    int fr2 = (int)(0xFFFFFFFFu - (unsigned)(k2 & 0xFFFFFFFFull));

    double lsum = 0.0, lcnt = 0.0;
    patch_body(&ts[w][0], lane, fr0, fr1, fr2, lsum, lcnt);

    for (int off = 32; off; off >>= 1) {
        lsum += __shfl_down(lsum, off, 64);
        lcnt += __shfl_down(lcnt, off, 64);
    }
    if (lane == 0) {
        if (pairs) {
            pairs[ser] = make_double2(lsum, lcnt);
        } else {
            atomicAdd(&acc[1], lsum);
            atomicAdd(&acc[2], lcnt);
        }
    }
}

// ---------------------------------------------------------------------------
__global__ __launch_bounds__(1024) void reduce_k(const double2* __restrict__ pairs,
                                                 const double* __restrict__ msep,
                                                 float* __restrict__ out) {
    const int tid = threadIdx.x;
    double ls = 0.0, lc = 0.0, ms = 0.0;
    for (int i = tid; i < NSER; i += 1024) {
        double2 p = pairs[i];
        ls += p.x; lc += p.y;
    }
    for (int i = tid; i < NMSEP; i += 1024) ms += msep[i];
    for (int off = 32; off; off >>= 1) {
        ls += __shfl_down(ls, off, 64);
        lc += __shfl_down(lc, off, 64);
        ms += __shfl_down(ms, off, 64);
    }
    __shared__ double sl[16], sc[16], sm[16];
    int lane = tid & 63, wid = tid >> 6;
    if (lane == 0) { sl[wid] = ls; sc[wid] = lc; sm[wid] = ms; }
    __syncthreads();
    if (tid == 0) {
        double L = 0, C = 0, M = 0;
        for (int i = 0; i < 16; i++) { L += sl[i]; C += sc[i]; M += sm[i]; }
        double mse = M / (double)((size_t)NB * TT * NF);
        double avg = (C > 0.0) ? (L / C) : 0.0;
        out[0] = (float)(0.5 * mse + 0.5 * avg);
    }
}

__global__ void finalize_k(const double* __restrict__ acc, float* __restrict__ out) {
    double mse = acc[0] / (double)((size_t)NB * TT * NF);
    double avg = (acc[2] > 0.0) ? (acc[1] / acc[2]) : 0.0;
    out[0] = (float)(0.5 * mse + 0.5 * avg);
}

// ---------------------------------------------------------------------------
extern "C" void kernel_launch(void* const* d_in, const int* in_sizes, int n_in,
                              void* d_out, int out_size, void* d_ws, size_t ws_size,
                              hipStream_t stream) {
    const float* fc = (const float*)d_in[0];   // forecast
    const float* tg = (const float*)d_in[1];   // target
    float* out = (float*)d_out;
    char* ws = (char*)d_ws;
    double* acc = (double*)ws;

    // layout: [0,64) acc | msep | pairs | topk | Wb | tsT
    const size_t OFF_MSE = 64;
    const size_t OFF_PAIR = OFF_MSE + (size_t)NMSEP * sizeof(double);        // 62016
    const size_t OFF_TOP = OFF_PAIR + (size_t)NSER * sizeof(double2);        // 390720
    const size_t OFF_W = OFF_TOP + (size_t)NSER * sizeof(uint4);             // 719424
    const size_t OFF_TS = OFF_W + (size_t)TT * KP * sizeof(unsigned short);  // 955968
    const size_t bytesT = (size_t)NSER * TT * sizeof(float2);
    const bool big2 = (ws_size >= OFF_TS + bytesT);
    const size_t R3_OFF_TS = OFF_PAIR + (size_t)NSER * sizeof(double2);
    const bool big = !big2 && (ws_size >= R3_OFF_TS + bytesT);
    const bool mid = !big2 && !big && (ws_size >= OFF_MSE + bytesT);

    double* msep = (double*)(ws + OFF_MSE);
    double2* pairs = (double2*)(ws + OFF_PAIR);
    uint4* topkBuf = (uint4*)(ws + OFF_TOP);
    unsigned short* Wb = (unsigned short*)(ws + OFF_W);

    dim3 tg_grid(TGX, TGY, NB);
    dim3 tg_blk(32, 8);

    if (big2) {
        float2* tsT = (float2*)(ws + OFF_TS);
        twiddle_k<<<TT, 128, 0, stream>>>(Wb);
        psd_k<<<NSER / SPB, 256, 0, stream>>>(tg, Wb, topkBuf);
        transpose_k<<<tg_grid, tg_blk, 0, stream>>>(fc, tg, tsT, msep, acc);
        patch_k<<<NSER / WPB, 64 * WPB, 0, stream>>>(tsT, topkBuf, pairs);
        reduce_k<<<1, 1024, 0, stream>>>(pairs, msep, out);
    } else if (big) {
        float2* tsT = (float2*)(ws + R3_OFF_TS);
        transpose_k<<<tg_grid, tg_blk, 0, stream>>>(fc, tg, tsT, msep, acc);
        series_k<<<NSER / WPB, 64 * WPB, 0, stream>>>(tsT, fc, tg, 1, pairs, acc);
        reduce_k<<<1, 1024, 0, stream>>>(pairs, msep, out);
    } else if (mid) {
        float2* tsT = (float2*)(ws + OFF_MSE);
        hipMemsetAsync(d_ws, 0, 64, stream);
        transpose_k<<<tg_grid, tg_blk, 0, stream>>>(fc, tg, tsT, nullptr, acc);
        series_k<<<NSER / WPB, 64 * WPB, 0, stream>>>(tsT, fc, tg, 1, nullptr, acc);
        finalize_k<<<1, 1, 0, stream>>>(acc, out);
    } else {
        hipMemsetAsync(d_ws, 0, 64, stream);
        mse_k<<<1024, 256, 0, stream>>>(fc, tg, acc);
        series_k<<<NSER / WPB, 64 * WPB, 0, stream>>>(nullptr, fc, tg, 0, nullptr, acc);
        finalize_k<<<1, 1, 0, stream>>>(acc, out);
    }
}

// Round 7
// 196.188 us; speedup vs baseline: 3.5841x; 1.0333x over previous
//
#include <hip/hip_runtime.h>
#include <hip/hip_bf16.h>

#define TT 336
#define NF 321
#define NB 64
#define NSER (NB * NF)   // 20544 series
#define WPB 4            // waves (series) per block in patch kernels
#define KP 352           // K padded to multiple of 32 for 16x16x32 MFMA
#define LDA 360          // LDS row stride (ushorts) in psd_k
#define SPB 16           // series per block in psd_k (grid = 1284)

// prefix-table skew: breaks stride-P bank conflicts (P=16/32 worst cases)
#define SK(b) ((b) + ((b) >> 5))
#define TBL 348          // >= SK(336)+1 = 347

// transpose grid: 11 x 11 x 64 blocks
#define TGX 11
#define TGY 11
#define NMSEP (TGX * TGY * NB)   // 7744 per-block MSE partials

typedef __attribute__((ext_vector_type(8))) short bf16x8;
typedef __attribute__((ext_vector_type(4))) float f32x4;
typedef unsigned long long ULL;

__device__ __forceinline__ unsigned short f2bf(float v) {
    unsigned x = __float_as_uint(v);
    x += 0x7FFFu + ((x >> 16) & 1u);   // RNE; inputs are finite
    return (unsigned short)(x >> 16);
}

// sorted-3 insert (a0 >= a1 >= a2)
__device__ __forceinline__ void ins3(ULL& a0, ULL& a1, ULL& a2, ULL x) {
    ULL hi = a0 > x ? a0 : x;
    ULL lo = a0 > x ? x : a0;
    a0 = hi;
    ULL hi1 = a1 > lo ? a1 : lo;
    ULL lo1 = a1 > lo ? lo : a1;
    a1 = hi1;
    a2 = a2 > lo1 ? a2 : lo1;
}

// ---------------------------------------------------------------------------
// Twiddle matrix: Wb[n][k], n=2(f-1) -> cos(2pi f k/336), n=2(f-1)+1 -> sin
// ---------------------------------------------------------------------------
__global__ void twiddle_k(unsigned short* __restrict__ Wb) {
    int n = blockIdx.x;          // 0..335
    int f = (n >> 1) + 1;
    int isSin = n & 1;
    for (int k = threadIdx.x; k < KP; k += blockDim.x) {
        float v = 0.0f;
        if (k < TT) {
            int r = (f * k) % TT;
            double ang = 6.283185307179586476925286766559 * (double)r / 336.0;
            v = isSin ? (float)sin(ang) : (float)cos(ang);
        }
        Wb[(size_t)n * KP + k] = f2bf(v);
    }
}

// ---------------------------------------------------------------------------
// PSD + top-3 via MFMA GEMM. Block = 16 series, 4 waves split 21 nt-tiles.
// ---------------------------------------------------------------------------
__global__ __launch_bounds__(256) void psd_k(const float* __restrict__ tgO,
                                             const unsigned short* __restrict__ Wb,
                                             uint4* __restrict__ topk) {
    __shared__ __align__(16) unsigned short sA[SPB][LDA];
    __shared__ ULL tk3[4][SPB][3];
    const int tid = threadIdx.x;
    const int serBase = blockIdx.x * SPB;

    {
        int f_l = tid & 15, tch = tid >> 4;   // 16 t-chunks of 21
        int ser = serBase + f_l;
        int bb = ser / NF, ff = ser - bb * NF;
        const float* base = tgO + (size_t)bb * TT * NF + ff;
        int t0 = tch * 21;
#pragma unroll 3
        for (int i = 0; i < 21; i++)
            sA[f_l][t0 + i] = f2bf(base[(size_t)(t0 + i) * NF]);
    }
    if (tid < SPB * 16) sA[tid >> 4][TT + (tid & 15)] = 0;   // K padding
    __syncthreads();

    const int wave = tid >> 6, lane = tid & 63;
    const int quad = lane >> 4, c = lane & 15;
    const unsigned short* aRow = &sA[c][quad * 8];   // A[m=c][k=quad*8+j]
    const int ntStart = wave * 5;
    const int ntEnd = (wave == 3) ? 21 : ntStart + 5;

    ULL t0k[4] = {0, 0, 0, 0}, t1k[4] = {0, 0, 0, 0}, t2k[4] = {0, 0, 0, 0};
    for (int nt = ntStart; nt < ntEnd; nt++) {
        const unsigned short* bRow = Wb + (size_t)(nt * 16 + c) * KP + quad * 8;
        f32x4 acc = (f32x4){0.f, 0.f, 0.f, 0.f};
#pragma unroll
        for (int ks = 0; ks < 11; ks++) {
            bf16x8 a = *(const bf16x8*)(aRow + ks * 32);
            bf16x8 b = *(const bf16x8*)(bRow + ks * 32);
            acc = __builtin_amdgcn_mfma_f32_16x16x32_bf16(a, b, acc, 0, 0, 0);
        }
        int n = nt * 16 + c;
        unsigned fidx = (unsigned)((n >> 1) + 1);
        unsigned ftag = 0xFFFFFFFFu - fidx;
        bool odd = (n & 1) != 0;
#pragma unroll
        for (int r = 0; r < 4; r++) {
            float v = acc[r];
            float p = v * v;
            p += __shfl_xor(p, 1, 64);            // pair cos/sin columns
            ULL key = odd ? 0ull
                          : (((ULL)__float_as_uint(p) << 32) | (ULL)ftag);
            ins3(t0k[r], t1k[r], t2k[r], key);
        }
    }
#pragma unroll
    for (int m = 2; m <= 8; m <<= 1) {
#pragma unroll
        for (int r = 0; r < 4; r++) {
            ULL b0 = __shfl_xor(t0k[r], m, 64);
            ULL b1 = __shfl_xor(t1k[r], m, 64);
            ULL b2 = __shfl_xor(t2k[r], m, 64);
            ins3(t0k[r], t1k[r], t2k[r], b0);
            ins3(t0k[r], t1k[r], t2k[r], b1);
            ins3(t0k[r], t1k[r], t2k[r], b2);
        }
    }
    if (c == 0) {
#pragma unroll
        for (int r = 0; r < 4; r++) {
            int s = quad * 4 + r;
            tk3[wave][s][0] = t0k[r];
            tk3[wave][s][1] = t1k[r];
            tk3[wave][s][2] = t2k[r];
        }
    }
    __syncthreads();
    if (tid < SPB) {
        ULL k0 = 0, k1 = 0, k2 = 0;
#pragma unroll
        for (int wv = 0; wv < 4; wv++) {
#pragma unroll
            for (int j = 0; j < 3; j++) ins3(k0, k1, k2, tk3[wv][tid][j]);
        }
        unsigned f0 = 0xFFFFFFFFu - (unsigned)(k0 & 0xFFFFFFFFull);
        unsigned f1 = 0xFFFFFFFFu - (unsigned)(k1 & 0xFFFFFFFFull);
        unsigned f2 = 0xFFFFFFFFu - (unsigned)(k2 & 0xFFFFFFFFull);
        topk[serBase + tid] = make_uint4(f0, f1, f2, 0u);
    }
}

// ---------------------------------------------------------------------------
// Kernel 1: transpose [B, T, F] -> interleaved float2{tg,fc}[B*F][T], fused MSE.
// ---------------------------------------------------------------------------
__global__ __launch_bounds__(256) void transpose_k(const float* __restrict__ fc,
                                                   const float* __restrict__ tg,
                                                   float2* __restrict__ out,
                                                   double* __restrict__ msep,
                                                   double* __restrict__ acc) {
    __shared__ float ta[32][33];
    __shared__ float tb[32][33];
    __shared__ double wacc[4];
    const int b = blockIdx.z;
    const int t0 = blockIdx.x * 32, f0 = blockIdx.y * 32;
    const int tx = threadIdx.x, ty = threadIdx.y;   // block (32, 8)
    const size_t base = (size_t)b * TT * NF;
    double ms = 0.0;
#pragma unroll
    for (int k = 0; k < 4; k++) {
        int t = t0 + ty + 8 * k, f = f0 + tx;
        if (t < TT && f < NF) {
            float a = tg[base + (size_t)t * NF + f];
            float c = fc[base + (size_t)t * NF + f];
            ta[ty + 8 * k][tx] = a;
            tb[ty + 8 * k][tx] = c;
            double d = (double)a - (double)c;
            ms += d * d;
        }
    }
    __syncthreads();
#pragma unroll
    for (int k = 0; k < 4; k++) {
        int f = f0 + ty + 8 * k, t = t0 + tx;
        if (t < TT && f < NF) {
            out[((size_t)b * NF + f) * TT + t] =
                make_float2(ta[tx][ty + 8 * k], tb[tx][ty + 8 * k]);
        }
    }
    for (int off = 32; off; off >>= 1) ms += __shfl_down(ms, off, 64);
    int flat = ty * 32 + tx;
    int lane = flat & 63, wid = flat >> 6;
    if (lane == 0) wacc[wid] = ms;
    __syncthreads();
    if (flat == 0) {
        double tot = wacc[0] + wacc[1] + wacc[2] + wacc[3];
        if (msep) {
            int blk = (blockIdx.z * TGY + blockIdx.y) * TGX + blockIdx.x;
            msep[blk] = tot;
        } else {
            atomicAdd(&acc[0], tot);
        }
    }
}

// ---------------------------------------------------------------------------
__global__ void mse_k(const float* __restrict__ fc, const float* __restrict__ tg,
                      double* __restrict__ acc) {
    const size_t N4 = (size_t)NB * TT * NF / 4;
    const float4* a4 = (const float4*)fc;
    const float4* b4 = (const float4*)tg;
    double s = 0.0;
    for (size_t i = (size_t)blockIdx.x * blockDim.x + threadIdx.x; i < N4;
         i += (size_t)gridDim.x * blockDim.x) {
        float4 a = a4[i], b = b4[i];
        double d0 = (double)a.x - (double)b.x;
        double d1 = (double)a.y - (double)b.y;
        double d2 = (double)a.z - (double)b.z;
        double d3 = (double)a.w - (double)b.w;
        s += d0 * d0 + d1 * d1 + d2 * d2 + d3 * d3;
    }
    for (int off = 32; off; off >>= 1) s += __shfl_down(s, off, 64);
    __shared__ double wsum[4];
    int flat = threadIdx.x;
    int lane = flat & 63, wid = flat >> 6;
    if (lane == 0) wsum[wid] = s;
    __syncthreads();
    if (flat == 0) atomicAdd(&acc[0], wsum[0] + wsum[1] + wsum[2] + wsum[3]);
}

// ---------------------------------------------------------------------------
__device__ __forceinline__ double patch_loss(double S1, double S2, double S3,
                                             double S4, double S5, double nn) {
    double mt = S1 / nn, mf = S2 / nn;
    double tvs = S3 - nn * mt * mt; tvs = tvs > 0.0 ? tvs : 0.0;
    double fvs = S4 - nn * mf * mf; fvs = fvs > 0.0 ? fvs : 0.0;
    double num = S5 - nn * mt * mf;
    double corr = num / (sqrt(tvs * fvs) + 1e-8);
    double closs = 1.0 - fabs(corr);
    double tvar = tvs / (nn - 1.0), fvar = fvs / (nn - 1.0);
    double vloss = fabs(tvar - fvar) / (tvar + 1e-8);
    double mloss = fabs(mt - mf) / (fabs(mt) + 1e-8);
    return closs + vloss + mloss;
}

// ---------------------------------------------------------------------------
struct PatchCfg {
    int P[3], nseg[3], rs[3];
    bool vp[3], hr[3];
};

__device__ __forceinline__ void make_cfg(int fr0, int fr1, int fr2, PatchCfg& c) {
    c.P[0] = TT / fr0; c.P[1] = TT / fr1; c.P[2] = TT / fr2;
    c.vp[0] = (c.P[0] >= 5);
    c.vp[1] = (c.P[1] >= 5) && (c.P[1] != c.P[0]);
    c.vp[2] = (c.P[2] >= 5) && (c.P[2] != c.P[0]) && (c.P[2] != c.P[1]);
#pragma unroll
    for (int q = 0; q < 3; q++) {
        c.nseg[q] = TT / c.P[q];
        c.rs[q] = c.nseg[q] * c.P[q];
        c.hr[q] = c.vp[q] && ((TT - c.rs[q]) >= 5);
    }
}

// slot i in [0,204) -> (s,e,kept) with dedup against earlier periods
__device__ __forceinline__ bool slot_patch(const PatchCfg& c, int i, int& s, int& e) {
    bool kept = false;
    s = 0; e = 0;
    if (i < 204) {
        int k = (i >= 136) ? 2 : ((i >= 68) ? 1 : 0);
        int si = i - k * 68;
        if (c.vp[k]) {
            if (si < c.nseg[k]) { s = c.P[k] * si; e = s + c.P[k]; kept = true; }
            else if (si == c.nseg[k] && c.hr[k]) { s = c.rs[k]; e = TT; kept = true; }
            if (kept) {
#pragma unroll
                for (int j = 0; j < 2; j++) {
                    if (j < k && c.vp[j]) {
                        bool dup = (s == c.rs[j]) && (e == TT) && c.hr[j];
                        int len = e - s;
                        // cheap guards first; int div/mod only for rare lanes
                        if (len == c.P[j] && s < c.rs[j] && (s % c.P[j]) == 0) dup = true;
                        if (dup) kept = false;
                    }
                }
            }
        }
    }
    return kept;
}

// ---------------------------------------------------------------------------
// Kernel: patch stats via per-element LDS prefix table (mixed precision).
// 4 waves/block, 1 series/wave. PS(b) = 5 LDS reads; no shfl gathers.
// S1,S2 fp64 (mean-sensitive: mloss ~ 1/mt^2); S3..S5 fp64-scan, fp32-store.
// ---------------------------------------------------------------------------
__global__ __launch_bounds__(256) void patch_k(const float2* __restrict__ tsG,
                                               const uint4* __restrict__ topk,
                                               double2* __restrict__ pairs) {
    const int w = threadIdx.x >> 6, lane = threadIdx.x & 63;
    const int ser = blockIdx.x * WPB + w;
    __shared__ double d1[WPB][TBL];
    __shared__ double d2[WPB][TBL];
    __shared__ float t3[WPB][TBL];
    __shared__ float t4[WPB][TBL];
    __shared__ float t5[WPB][TBL];

    // ---- load 6 contiguous elements per lane (lanes 0..55), 3x float4 ----
    const float2* sp = tsG + (size_t)ser * TT;
    float2 loc[6];
    double c1 = 0, c2 = 0, c3 = 0, c4 = 0, c5 = 0;
    if (lane < 56) {
        const float4* q4 = (const float4*)(sp + 6 * lane);
        float4 va = q4[0], vb = q4[1], vc = q4[2];
        loc[0] = make_float2(va.x, va.y); loc[1] = make_float2(va.z, va.w);
        loc[2] = make_float2(vb.x, vb.y); loc[3] = make_float2(vb.z, vb.w);
        loc[4] = make_float2(vc.x, vc.y); loc[5] = make_float2(vc.z, vc.w);
#pragma unroll
        for (int i = 0; i < 6; i++) {
            double a = loc[i].x, b = loc[i].y;
            c1 += a; c2 += b; c3 += a * a; c4 += b * b; c5 += a * b;
        }
    }

    // ---- inclusive scan over chunk sums (fp64 x5) ----
    double s1 = c1, s2 = c2, s3 = c3, s4 = c4, s5 = c5;
#pragma unroll
    for (int off = 1; off < 64; off <<= 1) {
        double y1 = __shfl_up(s1, off, 64);
        double y2 = __shfl_up(s2, off, 64);
        double y3 = __shfl_up(s3, off, 64);
        double y4 = __shfl_up(s4, off, 64);
        double y5 = __shfl_up(s5, off, 64);
        if (lane >= off) { s1 += y1; s2 += y2; s3 += y3; s4 += y4; s5 += y5; }
    }

    // ---- write per-element prefix table (skewed index) ----
    if (lane == 63) {
        d1[w][SK(0)] = 0.0; d2[w][SK(0)] = 0.0;
        t3[w][SK(0)] = 0.f; t4[w][SK(0)] = 0.f; t5[w][SK(0)] = 0.f;
    }
    if (lane < 56) {
        double r1 = s1 - c1, r2 = s2 - c2, r3 = s3 - c3, r4 = s4 - c4, r5 = s5 - c5;
#pragma unroll
        for (int i = 0; i < 6; i++) {
            double a = loc[i].x, b = loc[i].y;
            r1 += a; r2 += b; r3 += a * a; r4 += b * b; r5 += a * b;
            int ix = SK(6 * lane + i + 1);
            d1[w][ix] = r1; d2[w][ix] = r2;
            t3[w][ix] = (float)r3; t4[w][ix] = (float)r4; t5[w][ix] = (float)r5;
        }
    }
    __syncthreads();

    uint4 tk = topk[ser];
    PatchCfg cfg;
    make_cfg((int)tk.x, (int)tk.y, (int)tk.z, cfg);

    double lsum = 0.0, lcnt = 0.0;
    unsigned long long anyMask = 0ull;
#pragma unroll
    for (int rI = 0; rI < 4; rI++) {
        int s, e;
        bool kept = slot_patch(cfg, lane + 64 * rI, s, e);
        ULL bal = __ballot(kept);
        anyMask |= bal;
        if (bal == 0ull) continue;          // wave-uniform early-out
        if (kept) {
            int is = SK(s), ie = SK(e);
            double S1 = d1[w][ie] - d1[w][is];
            double S2 = d2[w][ie] - d2[w][is];
            double S3 = (double)t3[w][ie] - (double)t3[w][is];
            double S4 = (double)t4[w][ie] - (double)t4[w][is];
            double S5 = (double)t5[w][ie] - (double)t5[w][is];
            lsum += patch_loss(S1, S2, S3, S4, S5, (double)(e - s));
            lcnt += 1.0;
        }
    }

    // ---- fallback whole-series patch: table[336] ----
    if (anyMask == 0ull) {
        if (lane == 0) {
            int ie = SK(TT);
            lsum += patch_loss(d1[w][ie], d2[w][ie], (double)t3[w][ie],
                               (double)t4[w][ie], (double)t5[w][ie], (double)TT);
            lcnt += 1.0;
        }
    }

    for (int off = 32; off; off >>= 1) {
        lsum += __shfl_down(lsum, off, 64);
        lcnt += __shfl_down(lcnt, off, 64);
    }
    if (lane == 0) pairs[ser] = make_double2(lsum, lcnt);
}

// ---------------------------------------------------------------------------
// FALLBACK: self-contained series kernel (VALU DFT + topk + serial patches).
// ---------------------------------------------------------------------------
__device__ __forceinline__ void patch_body(const float2* tsw, int lane,
                                           int fr0, int fr1, int fr2,
                                           double& lsum, double& lcnt) {
    PatchCfg cfg;
    make_cfg(fr0, fr1, fr2, cfg);
    unsigned long long anyMask = 0ull;
#pragma unroll
    for (int rI = 0; rI < 4; rI++) {
        int s, e;
        bool kept = slot_patch(cfg, lane + 64 * rI, s, e);
        anyMask |= __ballot(kept);
        if (kept) {
            double S1 = 0, S2 = 0, S3 = 0, S4 = 0, S5 = 0;
            for (int t = s; t < e; t++) {
                float2 v = tsw[t];
                double a = (double)v.x, b = (double)v.y;
                S1 += a; S2 += b;
                S3 += a * a; S4 += b * b; S5 += a * b;
            }
            lsum += patch_loss(S1, S2, S3, S4, S5, (double)(e - s));
            lcnt += 1.0;
        }
    }
    if (anyMask == 0ull) {
        double S1 = 0, S2 = 0, S3 = 0, S4 = 0, S5 = 0;
        for (int t = lane; t < TT; t += 64) {
            float2 v = tsw[t];
            double a = (double)v.x, b = (double)v.y;
            S1 += a; S2 += b;
            S3 += a * a; S4 += b * b; S5 += a * b;
        }
        for (int off = 32; off; off >>= 1) {
            S1 += __shfl_down(S1, off, 64);
            S2 += __shfl_down(S2, off, 64);
            S3 += __shfl_down(S3, off, 64);
            S4 += __shfl_down(S4, off, 64);
            S5 += __shfl_down(S5, off, 64);
        }
        if (lane == 0) {
            lsum += patch_loss(S1, S2, S3, S4, S5, (double)TT);
            lcnt += 1.0;
        }
    }
}

__global__ __launch_bounds__(256, 6) void series_k(const float2* __restrict__ tsG,
                                                   const float* __restrict__ fcG,
                                                   const float* __restrict__ tgG,
                                                   int transposed,
                                                   double2* __restrict__ pairs,
                                                   double* __restrict__ acc) {
    const int w = threadIdx.x >> 6, lane = threadIdx.x & 63;
    const int ser = blockIdx.x * WPB + w;
    __shared__ float2 ts[WPB][TT];
    __shared__ float4 zb[WPB][84];

    if (transposed) {
        const float2* sp = tsG + (size_t)ser * TT;
        for (int t = lane; t < TT; t += 64) ts[w][t] = sp[t];
    } else {
        int b = ser / NF, f = ser - b * NF;
        const float* tp = tgG + (size_t)b * TT * NF + f;
        const float* fp = fcG + (size_t)b * TT * NF + f;
        for (int t = lane; t < TT; t += 64)
            ts[w][t] = make_float2(tp[(size_t)t * NF], fp[(size_t)t * NF]);
    }
    __syncthreads();

    for (int t = lane; t < 84; t += 64) {
        float x0 = ts[w][t].x, x1 = ts[w][t + 84].x;
        float x2 = ts[w][t + 168].x, x3 = ts[w][t + 252].x;
        float a = x0 + x2, b2 = x1 + x3, c = x0 - x2, d = x1 - x3;
        zb[w][t] = make_float4(a + b2, a - b2, c, d);
    }
    __syncthreads();

    const double TWOPI = 6.283185307179586476925286766559;
    int fb[3] = {1 + lane, 65 + lane, 129 + lane};
    float cc[3], sn[3], re[3], im[3], cd[3], sd[3], sgn[3];
    int selA[3];
#pragma unroll
    for (int q = 0; q < 3; q++) {
        int f = fb[q], cls = f & 3;
        double dl = (double)f * (TWOPI / 336.0);
        cd[q] = (float)cos(dl);
        sd[q] = (float)sin(dl);
        cc[q] = 1.0f; sn[q] = 0.0f; re[q] = 0.0f; im[q] = 0.0f;
        sgn[q] = (cls == 1) ? -1.0f : ((cls == 3) ? 1.0f : 0.0f);
        selA[q] = (cls == 0) ? 0 : ((cls == 2) ? 1 : 2);
    }
    for (int t = 0; t < 84; t++) {
        float4 zv = zb[w][t];
#pragma unroll
        for (int q = 0; q < 3; q++) {
            float zr = (selA[q] == 0) ? zv.x : ((selA[q] == 1) ? zv.y : zv.z);
            float zi = sgn[q] * zv.w;
            re[q] = fmaf(zr, cc[q], re[q]);
            re[q] = fmaf(zi, sn[q], re[q]);
            im[q] = fmaf(zi, cc[q], im[q]);
            im[q] = fmaf(-zr, sn[q], im[q]);
            float nc = fmaf(cc[q], cd[q], -(sn[q] * sd[q]));
            float ns = fmaf(sn[q], cd[q], cc[q] * sd[q]);
            cc[q] = nc; sn[q] = ns;
        }
    }

    ULL k0 = 0, k1 = 0, k2 = 0;
#pragma unroll
    for (int q = 0; q < 3; q++) {
        float a2 = fmaf(re[q], re[q], im[q] * im[q]);
        ULL key = ((ULL)__float_as_uint(a2) << 32) |
                  (ULL)(0xFFFFFFFFu - (unsigned)fb[q]);
        if (fb[q] > 168) key = 0ull;
        ins3(k0, k1, k2, key);
    }
    for (int m = 1; m < 64; m <<= 1) {
        ULL b0 = __shfl_xor(k0, m, 64);
        ULL b1 = __shfl_xor(k1, m, 64);
        ULL b2 = __shfl_xor(k2, m, 64);
        ins3(k0, k1, k2, b0); ins3(k0, k1, k2, b1); ins3(k0, k1, k2, b2);
    }

    int fr0 = (int)(0xFFFFFFFFu - (unsigned)(k0 & 0xFFFFFFFFull));
    int fr1 = (int)(0xFFFFFFFFu - (unsigned)(k1 & 0xFFFFFFFFull));
    int fr2 = (int)(0xFFFFFFFFu - (unsigned)(k2 & 0xFFFFFFFFull));

    double lsum = 0.0, lcnt = 0.0;
    patch_body(&ts[w][0], lane, fr0, fr1, fr2, lsum, lcnt);

    for (int off = 32; off; off >>= 1) {
        lsum += __shfl_down(lsum, off, 64);
        lcnt += __shfl_down(lcnt, off, 64);
    }
    if (lane == 0) {
        if (pairs) {
            pairs[ser] = make_double2(lsum, lcnt);
        } else {
            atomicAdd(&acc[1], lsum);
            atomicAdd(&acc[2], lcnt);
        }
    }
}

// ---------------------------------------------------------------------------
__global__ __launch_bounds__(1024) void reduce_k(const double2* __restrict__ pairs,
                                                 const double* __restrict__ msep,
                                                 float* __restrict__ out) {
    const int tid = threadIdx.x;
    double ls = 0.0, lc = 0.0, ms = 0.0;
    for (int i = tid; i < NSER; i += 1024) {
        double2 p = pairs[i];
        ls += p.x; lc += p.y;
    }
    for (int i = tid; i < NMSEP; i += 1024) ms += msep[i];
    for (int off = 32; off; off >>= 1) {
        ls += __shfl_down(ls, off, 64);
        lc += __shfl_down(lc, off, 64);
        ms += __shfl_down(ms, off, 64);
    }
    __shared__ double sl[16], sc[16], sm[16];
    int lane = tid & 63, wid = tid >> 6;
    if (lane == 0) { sl[wid] = ls; sc[wid] = lc; sm[wid] = ms; }
    __syncthreads();
    if (tid == 0) {
        double L = 0, C = 0, M = 0;
        for (int i = 0; i < 16; i++) { L += sl[i]; C += sc[i]; M += sm[i]; }
        double mse = M / (double)((size_t)NB * TT * NF);
        double avg = (C > 0.0) ? (L / C) : 0.0;
        out[0] = (float)(0.5 * mse + 0.5 * avg);
    }
}

__global__ void finalize_k(const double* __restrict__ acc, float* __restrict__ out) {
    double mse = acc[0] / (double)((size_t)NB * TT * NF);
    double avg = (acc[2] > 0.0) ? (acc[1] / acc[2]) : 0.0;
    out[0] = (float)(0.5 * mse + 0.5 * avg);
}

// ---------------------------------------------------------------------------
extern "C" void kernel_launch(void* const* d_in, const int* in_sizes, int n_in,
                              void* d_out, int out_size, void* d_ws, size_t ws_size,
                              hipStream_t stream) {
    const float* fc = (const float*)d_in[0];   // forecast
    const float* tg = (const float*)d_in[1];   // target
    float* out = (float*)d_out;
    char* ws = (char*)d_ws;
    double* acc = (double*)ws;

    // layout: [0,64) acc | msep | pairs | topk | Wb | tsT
    const size_t OFF_MSE = 64;
    const size_t OFF_PAIR = OFF_MSE + (size_t)NMSEP * sizeof(double);        // 62016
    const size_t OFF_TOP = OFF_PAIR + (size_t)NSER * sizeof(double2);        // 390720
    const size_t OFF_W = OFF_TOP + (size_t)NSER * sizeof(uint4);             // 719424
    const size_t OFF_TS = OFF_W + (size_t)TT * KP * sizeof(unsigned short);  // 955968
    const size_t bytesT = (size_t)NSER * TT * sizeof(float2);
    const bool big2 = (ws_size >= OFF_TS + bytesT);
    const size_t R3_OFF_TS = OFF_PAIR + (size_t)NSER * sizeof(double2);
    const bool big = !big2 && (ws_size >= R3_OFF_TS + bytesT);
    const bool mid = !big2 && !big && (ws_size >= OFF_MSE + bytesT);

    double* msep = (double*)(ws + OFF_MSE);
    double2* pairs = (double2*)(ws + OFF_PAIR);
    uint4* topkBuf = (uint4*)(ws + OFF_TOP);
    unsigned short* Wb = (unsigned short*)(ws + OFF_W);

    dim3 tg_grid(TGX, TGY, NB);
    dim3 tg_blk(32, 8);

    if (big2) {
        float2* tsT = (float2*)(ws + OFF_TS);
        twiddle_k<<<TT, 128, 0, stream>>>(Wb);
        psd_k<<<NSER / SPB, 256, 0, stream>>>(tg, Wb, topkBuf);
        transpose_k<<<tg_grid, tg_blk, 0, stream>>>(fc, tg, tsT, msep, acc);
        patch_k<<<NSER / WPB, 64 * WPB, 0, stream>>>(tsT, topkBuf, pairs);
        reduce_k<<<1, 1024, 0, stream>>>(pairs, msep, out);
    } else if (big) {
        float2* tsT = (float2*)(ws + R3_OFF_TS);
        transpose_k<<<tg_grid, tg_blk, 0, stream>>>(fc, tg, tsT, msep, acc);
        series_k<<<NSER / WPB, 64 * WPB, 0, stream>>>(tsT, fc, tg, 1, pairs, acc);
        reduce_k<<<1, 1024, 0, stream>>>(pairs, msep, out);
    } else if (mid) {
        float2* tsT = (float2*)(ws + OFF_MSE);
        hipMemsetAsync(d_ws, 0, 64, stream);
        transpose_k<<<tg_grid, tg_blk, 0, stream>>>(fc, tg, tsT, nullptr, acc);
        series_k<<<NSER / WPB, 64 * WPB, 0, stream>>>(tsT, fc, tg, 1, nullptr, acc);
        finalize_k<<<1, 1, 0, stream>>>(acc, out);
    } else {
        hipMemsetAsync(d_ws, 0, 64, stream);
        mse_k<<<1024, 256, 0, stream>>>(fc, tg, acc);
        series_k<<<NSER / WPB, 64 * WPB, 0, stream>>>(nullptr, fc, tg, 0, nullptr, acc);
        finalize_k<<<1, 1, 0, stream>>>(acc, out);
    }
}